// Round 11
// baseline (367.881 us; speedup 1.0000x reference)
//
#include <hip/hip_runtime.h>
#include <hip/hip_cooperative_groups.h>
#include <math.h>

namespace cg = cooperative_groups;

#define C_OUT 384
#define GAT_IN 24
#define HID 32
#define TSTEPS 12
#define NEG_SLOPE 0.2f
#define CAPW 64
#define SLOTS 96

__device__ __forceinline__ float sigm(float x) {
  return 1.f / (1.f + __expf(-x));
}
__device__ __forceinline__ float tanh_fast(float x) {
  return 2.f / (1.f + __expf(-2.f * x)) - 1.f;
}
__device__ __forceinline__ unsigned short f2bf(float x) {
  unsigned int u = __float_as_uint(x);
  unsigned int r = u + 0x7fffu + ((u >> 16) & 1u);
  return (unsigned short)(r >> 16);
}
__device__ __forceinline__ unsigned int packbf(float lo, float hi) {
  return (unsigned int)f2bf(lo) | ((unsigned int)f2bf(hi) << 16);
}
__device__ __forceinline__ float bf2f(unsigned short u) {
  return __uint_as_float((unsigned int)u << 16);
}
__device__ __forceinline__ float lrelu(float x) {
  return x >= 0.f ? x : NEG_SLOPE * x;
}

struct GiS { float At[24][68]; float Bt[24][100]; float bias[96]; };
struct AggS { float v[144]; int src[4][CAPW]; float w[4][CAPW][3]; };
struct RecS { float h[4][13][36]; float o[4][12]; };
union SMu { GiS gi; AggS agg; RecS rec; };

__global__ __launch_bounds__(256, 4) void k_fused(
    const float* __restrict__ xf, const int* __restrict__ esrc,
    const int* __restrict__ edst, const float* __restrict__ lin_w,
    const float* __restrict__ att_src, const float* __restrict__ att_dst,
    const float* __restrict__ gat_bias, const float* __restrict__ wih,
    const float* __restrict__ bih, const float* __restrict__ whh,
    const float* __restrict__ bhh, const float* __restrict__ p1w,
    const float* __restrict__ p1b, const float* __restrict__ p2w,
    const float* __restrict__ p2b, float* __restrict__ out,
    float* __restrict__ WW, float* __restrict__ vbuf, int* __restrict__ cnt,
    int* __restrict__ slist, float* __restrict__ Y,
    unsigned int* __restrict__ gib, int N, int E) {
  cg::grid_group gg = cg::this_grid();
  __shared__ SMu sm;
  const int tid = threadIdx.x;
  const int lane = tid & 63;
  const int wv = tid >> 6;
  const int T = gridDim.x * 256;
  const int tg = blockIdx.x * 256 + tid;

  // ======== phase 0: WW fold + vbuf prep + cnt zero ========
  for (int o = tg; o < 12 * 73 * 96; o += T) {
    int t = o / (73 * 96);
    int rem = o - t * (73 * 96);
    int k = rem / 96;
    int g = rem - k * 96;
    const float* wrow = wih + (size_t)g * HID;
    float acc = 0.f;
    if (k < 72) {
      int h = k / 24, j = k - (k / 24) * 24;
      const float* lp = lin_w + (size_t)(h * C_OUT + t * 32) * GAT_IN + j;
      for (int c = 0; c < 32; ++c)
        acc += (lp[(size_t)c * GAT_IN] * (1.f / 3.f)) * wrow[c];
    } else {
      for (int c = 0; c < 32; ++c) acc += gat_bias[t * 32 + c] * wrow[c];
      acc += bih[g];
    }
    WW[o] = acc;
  }
  {
    int wvg = tg >> 6;
    if (wvg < 72) {
      int h = wvg / 24, j = wvg - (wvg / 24) * 24;
      float as = 0.f, ad = 0.f;
      for (int c = lane; c < C_OUT; c += 64) {
        float wvv = lin_w[(size_t)(h * C_OUT + c) * GAT_IN + j];
        as += att_src[h * C_OUT + c] * wvv;
        ad += att_dst[h * C_OUT + c] * wvv;
      }
#pragma unroll
      for (int off = 32; off >= 1; off >>= 1) {
        as += __shfl_xor(as, off, 64);
        ad += __shfl_xor(ad, off, 64);
      }
      if (lane == 0) {
        vbuf[h * 24 + j] = as;
        vbuf[72 + h * 24 + j] = ad;
      }
    }
  }
  for (int i = tg; i < N; i += T) cnt[i] = 0;
  gg.sync();

  // ======== phase 1: bucket edges by dst ========
  for (int e = tg; e < E + N; e += T) {
    int d, s;
    if (e < E) { d = edst[e]; s = esrc[e]; }
    else { d = e - E; s = e - E; }
    int pos = atomicAdd(&cnt[d], 1);
    if (pos < SLOTS) slist[(size_t)d * SLOTS + pos] = s;
  }
  gg.sync();

  // ======== phase 2: logits + softmax + xf-space aggregation ========
  if (tid < 144) sm.agg.v[tid] = vbuf[tid];
  __syncthreads();
  {
    int ngrp = (N + 3) >> 2;
    for (int grp = blockIdx.x; grp < ngrp; grp += gridDim.x) {
      int n = grp * 4 + wv;
      bool act = n < N;
      int nc = act ? n : 0;
      int deg = act ? min(cnt[nc], SLOTS) : 0;

      float xl = (lane < 24) ? xf[(size_t)nc * 24 + lane] : 0.f;
      float p0 = (lane < 24) ? xl * sm.agg.v[72 + lane] : 0.f;
      float p1v = (lane < 24) ? xl * sm.agg.v[96 + lane] : 0.f;
      float p2v = (lane < 24) ? xl * sm.agg.v[120 + lane] : 0.f;
#pragma unroll
      for (int off = 32; off >= 1; off >>= 1) {
        p0 += __shfl_xor(p0, off, 64);
        p1v += __shfl_xor(p1v, off, 64);
        p2v += __shfl_xor(p2v, off, 64);
      }
      float ad0 = p0, ad1 = p1v, ad2 = p2v;

      float t0 = 0.f, t1 = 0.f, t2 = 0.f;
      for (int i = lane; i < deg; i += 64) {
        int s = slist[(size_t)nc * SLOTS + i];
        const float4* xr = (const float4*)(xf + (size_t)s * 24);
        float xs[24];
#pragma unroll
        for (int q = 0; q < 6; ++q) {
          float4 v = xr[q];
          xs[4 * q] = v.x; xs[4 * q + 1] = v.y;
          xs[4 * q + 2] = v.z; xs[4 * q + 3] = v.w;
        }
        float as0 = 0.f, as1 = 0.f, as2 = 0.f;
#pragma unroll
        for (int j = 0; j < 24; ++j) {
          float v = xs[j];
          as0 += v * sm.agg.v[j];
          as1 += v * sm.agg.v[24 + j];
          as2 += v * sm.agg.v[48 + j];
        }
        float e0 = __expf(lrelu(as0 + ad0));
        float e1 = __expf(lrelu(as1 + ad1));
        float e2 = __expf(lrelu(as2 + ad2));
        if (i < CAPW) {
          sm.agg.src[wv][i] = s;
          sm.agg.w[wv][i][0] = e0;
          sm.agg.w[wv][i][1] = e1;
          sm.agg.w[wv][i][2] = e2;
        }
        t0 += e0; t1 += e1; t2 += e2;
      }
#pragma unroll
      for (int off = 32; off >= 1; off >>= 1) {
        t0 += __shfl_xor(t0, off, 64);
        t1 += __shfl_xor(t1, off, 64);
        t2 += __shfl_xor(t2, off, 64);
      }
      float inv0 = 1.f / t0, inv1 = 1.f / t1, inv2 = 1.f / t2;

      int eg = lane >> 5;
      int c = lane & 31;
      float acc0 = 0.f, acc1 = 0.f, acc2 = 0.f;
      if (deg <= CAPW) {
#pragma unroll 2
        for (int i = eg; i < deg; i += 2) {
          int s = sm.agg.src[wv][i];
          float w0 = sm.agg.w[wv][i][0] * inv0;
          float w1 = sm.agg.w[wv][i][1] * inv1;
          float w2 = sm.agg.w[wv][i][2] * inv2;
          float xv = (c < 24) ? xf[(size_t)s * 24 + c] : 0.f;
          acc0 += w0 * xv; acc1 += w1 * xv; acc2 += w2 * xv;
        }
      } else {
        for (int i = eg; i < deg; i += 2) {
          int s = slist[(size_t)nc * SLOTS + i];
          float as0 = 0.f, as1 = 0.f, as2 = 0.f;
          const float* xr = xf + (size_t)s * 24;
#pragma unroll
          for (int j = 0; j < 24; ++j) {
            float v = xr[j];
            as0 += v * sm.agg.v[j];
            as1 += v * sm.agg.v[24 + j];
            as2 += v * sm.agg.v[48 + j];
          }
          float w0 = __expf(lrelu(as0 + ad0)) * inv0;
          float w1 = __expf(lrelu(as1 + ad1)) * inv1;
          float w2 = __expf(lrelu(as2 + ad2)) * inv2;
          float xv = (c < 24) ? xf[(size_t)s * 24 + c] : 0.f;
          acc0 += w0 * xv; acc1 += w1 * xv; acc2 += w2 * xv;
        }
      }
      acc0 += __shfl_xor(acc0, 32, 64);
      acc1 += __shfl_xor(acc1, 32, 64);
      acc2 += __shfl_xor(acc2, 32, 64);
      if (act && lane < 24) {
        float* yr = Y + (size_t)n * 72;
        yr[lane] = acc0;
        yr[24 + lane] = acc1;
        yr[48 + lane] = acc2;
      }
    }
  }
  gg.sync();

  // ======== phase 3: gi(bf16) = Y @ WW[t] + bb[t] ========
  {
    int ntiles = (N + 63) >> 6;
    int ntasks = ntiles * 12;
    int r0 = (tid & 15) * 4;
    int c0 = (tid >> 4) * 6;
    int rs = tid >> 2;
    int qs = tid & 3;
    for (int task = blockIdx.x; task < ntasks; task += gridDim.x) {
      int tt = task / ntiles;
      int row0 = (task - tt * ntiles) << 6;
      const float* WWt = WW + (size_t)tt * (73 * 96);
      __syncthreads();  // prev task's reads done before rewrites
      if (tid < 96) sm.gi.bias[tid] = WWt[72 * 96 + tid];
      float acc[4][6];
#pragma unroll
      for (int i = 0; i < 4; ++i)
#pragma unroll
        for (int j = 0; j < 6; ++j) acc[i][j] = 0.f;
      int rc = min(row0 + rs, N - 1);
#pragma unroll
      for (int ch = 0; ch < 3; ++ch) {
        const float* yp = Y + (size_t)rc * 72 + ch * 24 + qs * 6;
        float2 a0 = *(const float2*)yp;
        float2 a1 = *(const float2*)(yp + 2);
        float2 a2 = *(const float2*)(yp + 4);
        int kb = qs * 6;
        sm.gi.At[kb + 0][rs] = a0.x; sm.gi.At[kb + 1][rs] = a0.y;
        sm.gi.At[kb + 2][rs] = a1.x; sm.gi.At[kb + 3][rs] = a1.y;
        sm.gi.At[kb + 4][rs] = a2.x; sm.gi.At[kb + 5][rs] = a2.y;
        for (int fid = tid; fid < 576; fid += 256) {
          int k = fid / 24;
          int gq = (fid - k * 24) * 4;
          float4 b = *(const float4*)(WWt + (size_t)(ch * 24 + k) * 96 + gq);
          sm.gi.Bt[k][gq + 0] = b.x; sm.gi.Bt[k][gq + 1] = b.y;
          sm.gi.Bt[k][gq + 2] = b.z; sm.gi.Bt[k][gq + 3] = b.w;
        }
        __syncthreads();
#pragma unroll 4
        for (int k = 0; k < 24; ++k) {
          float4 a = *(const float4*)&sm.gi.At[k][r0];
          float2 b0 = *(const float2*)&sm.gi.Bt[k][c0];
          float2 b1 = *(const float2*)&sm.gi.Bt[k][c0 + 2];
          float2 b2 = *(const float2*)&sm.gi.Bt[k][c0 + 4];
          float bb[6] = {b0.x, b0.y, b1.x, b1.y, b2.x, b2.y};
          float av[4] = {a.x, a.y, a.z, a.w};
#pragma unroll
          for (int i = 0; i < 4; ++i)
#pragma unroll
            for (int j = 0; j < 6; ++j) acc[i][j] += av[i] * bb[j];
        }
        __syncthreads();
      }
#pragma unroll
      for (int i = 0; i < 4; ++i) {
        int n = row0 + r0 + i;
        if (n < N) {
          unsigned int* crow = gib + (size_t)n * 576 + (tt * 96 + c0) / 2;
          crow[0] = packbf(acc[i][0] + sm.gi.bias[c0 + 0],
                           acc[i][1] + sm.gi.bias[c0 + 1]);
          crow[1] = packbf(acc[i][2] + sm.gi.bias[c0 + 2],
                           acc[i][3] + sm.gi.bias[c0 + 3]);
          crow[2] = packbf(acc[i][4] + sm.gi.bias[c0 + 4],
                           acc[i][5] + sm.gi.bias[c0 + 5]);
        }
      }
    }
  }
  gg.sync();

  // ======== phase 4: GRU recurrence + projections ========
  {
    const unsigned short* gi16 = (const unsigned short*)gib;
    int kh = lane & 31;
    int jh = lane >> 5;
    const float4* pr = (const float4*)(whh + (size_t)kh * HID + jh * 16);
    const float4* pz = (const float4*)(whh + (size_t)(HID + kh) * HID + jh * 16);
    const float4* pn = (const float4*)(whh + (size_t)(2 * HID + kh) * HID + jh * 16);
    float4 wr0 = pr[0], wr1 = pr[1], wr2 = pr[2], wr3 = pr[3];
    float4 wz0 = pz[0], wz1 = pz[1], wz2 = pz[2], wz3 = pz[3];
    float4 wn0 = pn[0], wn1 = pn[1], wn2 = pn[2], wn3 = pn[3];
    float bhr = bhh[kh], bhz = bhh[HID + kh], bhn = bhh[2 * HID + kh];
    float p1b0 = p1b[0];
    int ngr = (N + 3) >> 2;
    for (int g4 = blockIdx.x; g4 < ngr; g4 += gridDim.x) {
      int node = g4 * 4 + wv;
      bool act = node < N;
      int nodec = act ? node : 0;
      if (jh == 0) sm.rec.h[wv][0][kh] = 0.f;
      float h = 0.f;
      const unsigned short* gbase = gi16 + (size_t)nodec * TSTEPS * 96;
      float gr = bf2f(gbase[kh]);
      float gz = bf2f(gbase[32 + kh]);
      float gn = bf2f(gbase[64 + kh]);
      for (int t = 0; t < TSTEPS; ++t) {
        float gr1 = 0.f, gz1 = 0.f, gn1 = 0.f;
        if (t + 1 < TSTEPS) {
          const unsigned short* pa = gbase + (t + 1) * 96;
          gr1 = bf2f(pa[kh]); gz1 = bf2f(pa[32 + kh]); gn1 = bf2f(pa[64 + kh]);
        }
        const float* hh = &sm.rec.h[wv][t][jh * 16];
        float4 h0 = *(const float4*)(hh);
        float4 h1 = *(const float4*)(hh + 4);
        float4 h2 = *(const float4*)(hh + 8);
        float4 h3 = *(const float4*)(hh + 12);
        float ar = wr0.x * h0.x + wr0.y * h0.y + wr0.z * h0.z + wr0.w * h0.w +
                   wr1.x * h1.x + wr1.y * h1.y + wr1.z * h1.z + wr1.w * h1.w +
                   wr2.x * h2.x + wr2.y * h2.y + wr2.z * h2.z + wr2.w * h2.w +
                   wr3.x * h3.x + wr3.y * h3.y + wr3.z * h3.z + wr3.w * h3.w;
        float az = wz0.x * h0.x + wz0.y * h0.y + wz0.z * h0.z + wz0.w * h0.w +
                   wz1.x * h1.x + wz1.y * h1.y + wz1.z * h1.z + wz1.w * h1.w +
                   wz2.x * h2.x + wz2.y * h2.y + wz2.z * h2.z + wz2.w * h2.w +
                   wz3.x * h3.x + wz3.y * h3.y + wz3.z * h3.z + wz3.w * h3.w;
        float an = wn0.x * h0.x + wn0.y * h0.y + wn0.z * h0.z + wn0.w * h0.w +
                   wn1.x * h1.x + wn1.y * h1.y + wn1.z * h1.z + wn1.w * h1.w +
                   wn2.x * h2.x + wn2.y * h2.y + wn2.z * h2.z + wn2.w * h2.w +
                   wn3.x * h3.x + wn3.y * h3.y + wn3.z * h3.z + wn3.w * h3.w;
        ar += __shfl_xor(ar, 32, 64);
        az += __shfl_xor(az, 32, 64);
        an += __shfl_xor(an, 32, 64);
        float r = sigm(gr + ar + bhr);
        float z = sigm(gz + az + bhz);
        float nn = tanh_fast(gn + r * (an + bhn));
        h = (1.f - z) * nn + z * h;
        if (jh == 0) sm.rec.h[wv][t + 1][kh] = h;
        gr = gr1; gz = gz1; gn = gn1;
      }
      if (act && jh == 0 && kh < TSTEPS) {
        float o = p1b0;
#pragma unroll
        for (int kk = 0; kk < HID; ++kk)
          o += sm.rec.h[wv][kh + 1][kk] * p1w[kk];
        sm.rec.o[wv][kh] = o;
      }
      if (act && jh == 0 && kh < TSTEPS) {
        float acc = p2b[kh];
#pragma unroll
        for (int s2 = 0; s2 < TSTEPS; ++s2)
          acc += p2w[kh * TSTEPS + s2] * sm.rec.o[wv][s2];
        out[(size_t)node * TSTEPS + kh] = acc;
      }
    }
  }
}

// ---------------------------------------------------------------------------
extern "C" void kernel_launch(void* const* d_in, const int* in_sizes, int n_in,
                              void* d_out, int out_size, void* d_ws,
                              size_t ws_size, hipStream_t stream) {
  const float* xf = (const float*)d_in[0];
  const int* ei = (const int*)d_in[1];
  const float* lin_w = (const float*)d_in[2];
  const float* att_src = (const float*)d_in[3];
  const float* att_dst = (const float*)d_in[4];
  const float* gat_bias = (const float*)d_in[5];
  const float* wih = (const float*)d_in[6];
  const float* whh = (const float*)d_in[7];
  const float* bih = (const float*)d_in[8];
  const float* bhh = (const float*)d_in[9];
  const float* p1w = (const float*)d_in[10];
  const float* p1b = (const float*)d_in[11];
  const float* p2w = (const float*)d_in[12];
  const float* p2b = (const float*)d_in[13];

  int N = in_sizes[0] / GAT_IN;  // 10000
  int E = in_sizes[1] / 2;       // 160000

  size_t off = 0;
  char* base = (char*)d_ws;
  auto alloc = [&](size_t bytes) {
    void* p = base + off;
    off += (bytes + 255) & ~(size_t)255;
    return p;
  };
  unsigned int* gib = (unsigned int*)alloc((size_t)N * 576 * 4);
  float* Yb = (float*)alloc((size_t)N * 72 * 4);
  float* WW = (float*)alloc((size_t)12 * 73 * 96 * 4);
  float* vbuf = (float*)alloc(144 * 4);
  int* cnt = (int*)alloc((size_t)N * 4);
  int* slist = (int*)alloc((size_t)N * SLOTS * 4);
  (void)ws_size; (void)n_in; (void)out_size;

  const int* pesrc = ei;
  const int* pedst = ei + E;
  float* outp = (float*)d_out;

  int maxb = 0;
  if (hipOccupancyMaxActiveBlocksPerMultiprocessor(&maxb, k_fused, 256, 0) !=
          hipSuccess ||
      maxb < 1)
    maxb = 1;
  int dev = 0;
  hipGetDevice(&dev);
  int ncu = 0;
  if (hipDeviceGetAttribute(&ncu, hipDeviceAttributeMultiprocessorCount,
                            dev) != hipSuccess ||
      ncu <= 0)
    ncu = 256;
  long long g = (long long)maxb * (long long)ncu;
  if (g > 2048) g = 2048;

  void* args[] = {(void*)&xf,      (void*)&pesrc,   (void*)&pedst,
                  (void*)&lin_w,   (void*)&att_src, (void*)&att_dst,
                  (void*)&gat_bias,(void*)&wih,     (void*)&bih,
                  (void*)&whh,     (void*)&bhh,     (void*)&p1w,
                  (void*)&p1b,     (void*)&p2w,     (void*)&p2b,
                  (void*)&outp,    (void*)&WW,      (void*)&vbuf,
                  (void*)&cnt,     (void*)&slist,   (void*)&Yb,
                  (void*)&gib,     (void*)&N,       (void*)&E};
  hipLaunchCooperativeKernel((const void*)k_fused, dim3((unsigned)g),
                             dim3(256), args, 0, stream);
}

// Round 12
// 99.540 us; speedup vs baseline: 3.6958x; 3.6958x over previous
//
#include <hip/hip_runtime.h>
#include <math.h>

#define HEADS 3
#define C_OUT 384
#define GAT_IN 24
#define HID 32
#define TSTEPS 12
#define NEG_SLOPE 0.2f
#define CAPW 64        // per-wave cached edges in k_aggx
#define SLOTS 96       // fixed slist stride per dst (P(deg>=96) ~ 1e-30)

__device__ __forceinline__ float sigm(float x) {
  return 1.f / (1.f + __expf(-x));
}
__device__ __forceinline__ float tanh_fast(float x) {
  return 2.f / (1.f + __expf(-2.f * x)) - 1.f;
}
__device__ __forceinline__ unsigned short f2bf(float x) {
  unsigned int u = __float_as_uint(x);
  unsigned int r = u + 0x7fffu + ((u >> 16) & 1u);
  return (unsigned short)(r >> 16);
}
__device__ __forceinline__ unsigned int packbf(float lo, float hi) {
  return (unsigned int)f2bf(lo) | ((unsigned int)f2bf(hi) << 16);
}
__device__ __forceinline__ float bf2f(unsigned short u) {
  return __uint_as_float((unsigned int)u << 16);
}
__device__ __forceinline__ float lrelu(float x) {
  return x >= 0.f ? x : NEG_SLOPE * x;
}

// ---------------- K_const: WW fold (0..875) + prep (876..947) + cnt zero ---
__global__ __launch_bounds__(96) void k_const(const float* __restrict__ lin_w,
                                              const float* __restrict__ gat_bias,
                                              const float* __restrict__ wih,
                                              const float* __restrict__ bih,
                                              const float* __restrict__ att_src,
                                              const float* __restrict__ att_dst,
                                              float* __restrict__ WW,
                                              float* __restrict__ vbuf,
                                              int* __restrict__ cnt, int N) {
  int b = blockIdx.x;
  if (b < 876) {  // fold
    int t = b / 73, k = b % 73;
    int g = threadIdx.x;  // 0..95
    __shared__ float s_w[32];
    if (g < 32) {
      if (k < 72) {
        int h = k / 24, j = k % 24;
        s_w[g] = lin_w[(size_t)(h * C_OUT + t * 32 + g) * GAT_IN + j] * (1.f / 3.f);
      } else {
        s_w[g] = gat_bias[t * 32 + g];
      }
    }
    __syncthreads();
    const float* wrow = wih + (size_t)g * 32;
    float acc = 0.f;
#pragma unroll
    for (int c = 0; c < 32; ++c) acc += s_w[c] * wrow[c];
    if (k == 72) acc += bih[g];
    WW[((size_t)t * 73 + k) * 96 + g] = acc;
  } else if (b < 948) {  // prep (single wave)
    int bb = b - 876;  // 0..71
    int h = bb / 24, j = bb % 24;
    int lane = threadIdx.x;
    if (lane >= 64) return;
    float as = 0.f, ad = 0.f;
    for (int c = lane; c < C_OUT; c += 64) {
      float wv = lin_w[(size_t)(h * C_OUT + c) * GAT_IN + j];
      as += att_src[h * C_OUT + c] * wv;
      ad += att_dst[h * C_OUT + c] * wv;
    }
#pragma unroll
    for (int off = 32; off >= 1; off >>= 1) {
      as += __shfl_xor(as, off, 64);
      ad += __shfl_xor(ad, off, 64);
    }
    if (lane == 0) {
      vbuf[h * 24 + j] = as;
      vbuf[72 + h * 24 + j] = ad;
    }
  } else {  // zero cnt
    int i = (b - 948) * 96 + threadIdx.x;
    if (i < N) cnt[i] = 0;
  }
}

// ---------------- K_place: bucket edges by dst, fixed stride ---------------
__global__ void k_place(const int* __restrict__ esrc,
                        const int* __restrict__ edst, int* __restrict__ cnt,
                        int* __restrict__ slist, int E, int ET) {
  int e = blockIdx.x * blockDim.x + threadIdx.x;
  if (e >= ET) return;
  int d, s;
  if (e < E) { d = edst[e]; s = esrc[e]; }
  else { d = e - E; s = e - E; }
  int pos = atomicAdd(&cnt[d], 1);
  if (pos < SLOTS) slist[(size_t)d * SLOTS + pos] = s;
}

// ---------------- K6: logits + softmax + xf-space aggregation --------------
// One dst node per 64-lane wave, 4 waves/block. Logits recomputed in-wave
// from xf; xf rows cached in LDS during pass A so pass B is LDS-only.
__global__ __launch_bounds__(256) void k_aggx(
    const float* __restrict__ xf, const float* __restrict__ vbuf,
    const int* __restrict__ slist, const int* __restrict__ cnt,
    float* __restrict__ Y, int N) {
  __shared__ float s_v[144];
  __shared__ int s_src[4][CAPW];
  __shared__ float s_w[4][CAPW][3];
  __shared__ float s_x[4][CAPW][25];  // cached xf rows (pad 25: conflict-free)
  int tid = threadIdx.x, lane = tid & 63, wv = tid >> 6;
  if (tid < 144) s_v[tid] = vbuf[tid];
  __syncthreads();  // before any wave can exit
  int n = blockIdx.x * 4 + wv;
  if (n >= N) return;  // per-wave exit; no barriers below

  int deg = min(cnt[n], SLOTS);

  // a_dst[n][h] = xf[n] . v_dst[h] : lanes 0..23 hold xf, xor-reduce
  float xl = (lane < 24) ? xf[(size_t)n * 24 + lane] : 0.f;
  float ad0, ad1, ad2;
  {
    float p0 = (lane < 24) ? xl * s_v[72 + lane] : 0.f;
    float p1 = (lane < 24) ? xl * s_v[96 + lane] : 0.f;
    float p2 = (lane < 24) ? xl * s_v[120 + lane] : 0.f;
#pragma unroll
    for (int off = 32; off >= 1; off >>= 1) {
      p0 += __shfl_xor(p0, off, 64);
      p1 += __shfl_xor(p1, off, 64);
      p2 += __shfl_xor(p2, off, 64);
    }
    ad0 = p0; ad1 = p1; ad2 = p2;
  }

  // pass A: per-edge logits from xf (6 float4 L2 loads + 72 FMA), exp, sum;
  // xf row and weights cached in LDS for pass B.
  float t0 = 0.f, t1 = 0.f, t2 = 0.f;
  for (int i = lane; i < deg; i += 64) {
    int s = slist[(size_t)n * SLOTS + i];
    const float4* xr = (const float4*)(xf + (size_t)s * 24);
    float xs[24];
#pragma unroll
    for (int q = 0; q < 6; ++q) {
      float4 v = xr[q];
      xs[4 * q] = v.x; xs[4 * q + 1] = v.y;
      xs[4 * q + 2] = v.z; xs[4 * q + 3] = v.w;
    }
    float as0 = 0.f, as1 = 0.f, as2 = 0.f;
#pragma unroll
    for (int j = 0; j < 24; ++j) {
      float v = xs[j];
      as0 += v * s_v[j];
      as1 += v * s_v[24 + j];
      as2 += v * s_v[48 + j];
    }
    float e0 = __expf(lrelu(as0 + ad0));
    float e1 = __expf(lrelu(as1 + ad1));
    float e2 = __expf(lrelu(as2 + ad2));
    if (i < CAPW) {
      s_src[wv][i] = s;
      s_w[wv][i][0] = e0; s_w[wv][i][1] = e1; s_w[wv][i][2] = e2;
#pragma unroll
      for (int j = 0; j < 24; ++j) s_x[wv][i][j] = xs[j];
    }
    t0 += e0; t1 += e1; t2 += e2;
  }
#pragma unroll
  for (int off = 32; off >= 1; off >>= 1) {
    t0 += __shfl_xor(t0, off, 64);
    t1 += __shfl_xor(t1, off, 64);
    t2 += __shfl_xor(t2, off, 64);
  }
  float inv0 = 1.f / t0, inv1 = 1.f / t1, inv2 = 1.f / t2;

  // pass B: 2 edge-slots x 24 active channel-lanes; all reads from LDS
  int eg = lane >> 5;   // edge slot 0/1
  int c = lane & 31;    // channel (active c<24)
  float acc0 = 0.f, acc1 = 0.f, acc2 = 0.f;
  if (deg <= CAPW) {
    int cc = (c < 24) ? c : 0;
    float cmask = (c < 24) ? 1.f : 0.f;
#pragma unroll 2
    for (int i = eg; i < deg; i += 2) {
      float w0 = s_w[wv][i][0] * inv0;
      float w1 = s_w[wv][i][1] * inv1;
      float w2 = s_w[wv][i][2] * inv2;
      float xv = s_x[wv][i][cc] * cmask;
      acc0 += w0 * xv; acc1 += w1 * xv; acc2 += w2 * xv;
    }
  } else {
    for (int i = eg; i < deg; i += 2) {
      int s = slist[(size_t)n * SLOTS + i];
      float as0 = 0.f, as1 = 0.f, as2 = 0.f;
      const float* xr = xf + (size_t)s * 24;
#pragma unroll
      for (int j = 0; j < 24; ++j) {
        float v = xr[j];
        as0 += v * s_v[j];
        as1 += v * s_v[24 + j];
        as2 += v * s_v[48 + j];
      }
      float w0 = __expf(lrelu(as0 + ad0)) * inv0;
      float w1 = __expf(lrelu(as1 + ad1)) * inv1;
      float w2 = __expf(lrelu(as2 + ad2)) * inv2;
      float xv = (c < 24) ? xf[(size_t)s * 24 + c] : 0.f;
      acc0 += w0 * xv; acc1 += w1 * xv; acc2 += w2 * xv;
    }
  }
  acc0 += __shfl_xor(acc0, 32, 64);
  acc1 += __shfl_xor(acc1, 32, 64);
  acc2 += __shfl_xor(acc2, 32, 64);
  if (lane < 24) {
    float* yr = Y + (size_t)n * 72;
    yr[lane] = acc0;
    yr[24 + lane] = acc1;
    yr[48 + lane] = acc2;
  }
}

// ---------------- K_gi2: gi(bf16) = Y @ WW[t] + bb[t], K-chunked -----------
__global__ __launch_bounds__(128) void k_gi2(const float* __restrict__ Y,
                                             const float* __restrict__ WW,
                                             unsigned int* __restrict__ gi,
                                             int N) {
  __shared__ float At[24][68];
  __shared__ float Bt[24][100];
  __shared__ float s_bias[96];
  int tid = threadIdx.x;
  int row0 = blockIdx.x * 64;
  int t = blockIdx.y;
  const float* WWt = WW + (size_t)t * 73 * 96;
  if (tid < 96) s_bias[tid] = WWt[72 * 96 + tid];
  int r0 = (tid & 7) * 8, c0 = (tid >> 3) * 6;
  float acc[8][6];
#pragma unroll
  for (int i = 0; i < 8; ++i)
#pragma unroll
    for (int j = 0; j < 6; ++j) acc[i][j] = 0.f;

  int r = tid >> 1, half = tid & 1;
  int rc = min(row0 + r, N - 1);
#pragma unroll
  for (int ch = 0; ch < 3; ++ch) {
    {
      const float4* yr =
          (const float4*)(Y + (size_t)rc * 72 + ch * 24 + half * 12);
#pragma unroll
      for (int q = 0; q < 3; ++q) {
        float4 a = yr[q];
        int kk = half * 12 + q * 4;
        At[kk + 0][r] = a.x; At[kk + 1][r] = a.y;
        At[kk + 2][r] = a.z; At[kk + 3][r] = a.w;
      }
    }
#pragma unroll
    for (int fid = tid; fid < 576; fid += 128) {
      int k = fid / 24, gq = (fid % 24) * 4;
      float4 b = *(const float4*)(WWt + (size_t)(ch * 24 + k) * 96 + gq);
      Bt[k][gq + 0] = b.x; Bt[k][gq + 1] = b.y;
      Bt[k][gq + 2] = b.z; Bt[k][gq + 3] = b.w;
    }
    __syncthreads();
#pragma unroll 4
    for (int k = 0; k < 24; ++k) {
      float4 a0 = *(const float4*)&At[k][r0];
      float4 a1 = *(const float4*)&At[k][r0 + 4];
      float2 b0 = *(const float2*)&Bt[k][c0];
      float2 b1 = *(const float2*)&Bt[k][c0 + 2];
      float2 b2 = *(const float2*)&Bt[k][c0 + 4];
      float b[6] = {b0.x, b0.y, b1.x, b1.y, b2.x, b2.y};
      float av[8] = {a0.x, a0.y, a0.z, a0.w, a1.x, a1.y, a1.z, a1.w};
#pragma unroll
      for (int i = 0; i < 8; ++i)
#pragma unroll
        for (int j = 0; j < 6; ++j) acc[i][j] += av[i] * b[j];
    }
    __syncthreads();
  }
#pragma unroll
  for (int i = 0; i < 8; ++i) {
    int n = row0 + r0 + i;
    if (n < N) {
      unsigned int* crow = gi + (size_t)n * 576 + (t * 96 + c0) / 2;
#pragma unroll
      for (int jj = 0; jj < 3; ++jj) {
        float lo = acc[i][2 * jj] + s_bias[c0 + 2 * jj];
        float hi = acc[i][2 * jj + 1] + s_bias[c0 + 2 * jj + 1];
        crow[jj] = packbf(lo, hi);
      }
    }
  }
}

// ---------------- K7b: GRU recurrence + projections ------------------------
__global__ __launch_bounds__(256, 4) void k_rec(
    const unsigned short* __restrict__ gi, const float* __restrict__ whh,
    const float* __restrict__ bhh, const float* __restrict__ p1w,
    const float* __restrict__ p1b, const float* __restrict__ p2w,
    const float* __restrict__ p2b, float* __restrict__ out, int N) {
  __shared__ float h_hist[4][13][36];
  __shared__ float s_o[4][12];
  int tid = threadIdx.x;
  int wv = tid >> 6;   // node slot 0..3
  int lane = tid & 63;
  int k = lane & 31;   // hidden unit
  int jh = lane >> 5;  // j-half: 0 -> h[0..15], 1 -> h[16..31]
  int node = blockIdx.x * 4 + wv;
  if (node >= N) return;  // per-wave exit; no barriers below

  const float4* pr = (const float4*)(whh + (size_t)k * HID + jh * 16);
  const float4* pz = (const float4*)(whh + (size_t)(HID + k) * HID + jh * 16);
  const float4* pn = (const float4*)(whh + (size_t)(2 * HID + k) * HID + jh * 16);
  float4 wr0 = pr[0], wr1 = pr[1], wr2 = pr[2], wr3 = pr[3];
  float4 wz0 = pz[0], wz1 = pz[1], wz2 = pz[2], wz3 = pz[3];
  float4 wn0 = pn[0], wn1 = pn[1], wn2 = pn[2], wn3 = pn[3];
  float bhr = bhh[k], bhz = bhh[HID + k], bhn = bhh[2 * HID + k];

  if (jh == 0) h_hist[wv][0][k] = 0.f;
  float h = 0.f;
  const unsigned short* gbase = gi + (size_t)node * TSTEPS * 96;
  float gr = bf2f(gbase[k]), gz = bf2f(gbase[32 + k]), gn = bf2f(gbase[64 + k]);

  for (int t = 0; t < TSTEPS; ++t) {
    float gr1 = 0.f, gz1 = 0.f, gn1 = 0.f;
    if (t + 1 < TSTEPS) {
      const unsigned short* pa = gbase + (t + 1) * 96;
      gr1 = bf2f(pa[k]); gz1 = bf2f(pa[32 + k]); gn1 = bf2f(pa[64 + k]);
    }
    const float* hh = &h_hist[wv][t][jh * 16];
    float4 h0 = *(const float4*)(hh);
    float4 h1 = *(const float4*)(hh + 4);
    float4 h2 = *(const float4*)(hh + 8);
    float4 h3 = *(const float4*)(hh + 12);
    float ar = wr0.x * h0.x + wr0.y * h0.y + wr0.z * h0.z + wr0.w * h0.w +
               wr1.x * h1.x + wr1.y * h1.y + wr1.z * h1.z + wr1.w * h1.w +
               wr2.x * h2.x + wr2.y * h2.y + wr2.z * h2.z + wr2.w * h2.w +
               wr3.x * h3.x + wr3.y * h3.y + wr3.z * h3.z + wr3.w * h3.w;
    float az = wz0.x * h0.x + wz0.y * h0.y + wz0.z * h0.z + wz0.w * h0.w +
               wz1.x * h1.x + wz1.y * h1.y + wz1.z * h1.z + wz1.w * h1.w +
               wz2.x * h2.x + wz2.y * h2.y + wz2.z * h2.z + wz2.w * h2.w +
               wz3.x * h3.x + wz3.y * h3.y + wz3.z * h3.z + wz3.w * h3.w;
    float an = wn0.x * h0.x + wn0.y * h0.y + wn0.z * h0.z + wn0.w * h0.w +
               wn1.x * h1.x + wn1.y * h1.y + wn1.z * h1.z + wn1.w * h1.w +
               wn2.x * h2.x + wn2.y * h2.y + wn2.z * h2.z + wn2.w * h2.w +
               wn3.x * h3.x + wn3.y * h3.y + wn3.z * h3.z + wn3.w * h3.w;
    ar += __shfl_xor(ar, 32, 64);
    az += __shfl_xor(az, 32, 64);
    an += __shfl_xor(an, 32, 64);
    float r = sigm(gr + ar + bhr);
    float z = sigm(gz + az + bhz);
    float nn = tanh_fast(gn + r * (an + bhn));
    h = (1.f - z) * nn + z * h;
    if (jh == 0) h_hist[wv][t + 1][k] = h;
    gr = gr1; gz = gz1; gn = gn1;
  }
  if (jh == 0 && k < TSTEPS) {
    float o = p1b[0];
#pragma unroll
    for (int kk = 0; kk < HID; ++kk) o += h_hist[wv][k + 1][kk] * p1w[kk];
    s_o[wv][k] = o;
  }
  if (jh == 0 && k < TSTEPS) {
    float acc = p2b[k];
#pragma unroll
    for (int s2 = 0; s2 < TSTEPS; ++s2)
      acc += p2w[k * TSTEPS + s2] * s_o[wv][s2];
    out[(size_t)node * TSTEPS + k] = acc;
  }
}

// ---------------------------------------------------------------------------
extern "C" void kernel_launch(void* const* d_in, const int* in_sizes, int n_in,
                              void* d_out, int out_size, void* d_ws,
                              size_t ws_size, hipStream_t stream) {
  const float* x = (const float*)d_in[0];
  const int* ei = (const int*)d_in[1];
  const float* lin_w = (const float*)d_in[2];
  const float* att_src = (const float*)d_in[3];
  const float* att_dst = (const float*)d_in[4];
  const float* gat_bias = (const float*)d_in[5];
  const float* w_ih = (const float*)d_in[6];
  const float* w_hh = (const float*)d_in[7];
  const float* b_ih = (const float*)d_in[8];
  const float* b_hh = (const float*)d_in[9];
  const float* p1w = (const float*)d_in[10];
  const float* p1b = (const float*)d_in[11];
  const float* p2w = (const float*)d_in[12];
  const float* p2b = (const float*)d_in[13];

  int N = in_sizes[0] / GAT_IN;  // 10000
  int E = in_sizes[1] / 2;       // 160000
  int ET = E + N;

  size_t off = 0;
  char* base = (char*)d_ws;
  auto alloc = [&](size_t bytes) {
    void* p = base + off;
    off += (bytes + 255) & ~(size_t)255;
    return p;
  };
  unsigned int* gib = (unsigned int*)alloc((size_t)N * 576 * 4);  // bf16 gi
  float* Yb = (float*)alloc((size_t)N * 72 * 4);
  float* WW = (float*)alloc((size_t)12 * 73 * 96 * 4);
  float* vbuf = (float*)alloc(144 * 4);
  int* cnt = (int*)alloc((size_t)N * 4);
  int* slist = (int*)alloc((size_t)N * SLOTS * 4);
  (void)ws_size; (void)n_in; (void)out_size;

  int zero_blocks = (N + 95) / 96;  // 105
  k_const<<<948 + zero_blocks, 96, 0, stream>>>(lin_w, gat_bias, w_ih, b_ih,
                                                att_src, att_dst, WW, vbuf,
                                                cnt, N);
  k_place<<<(ET + 255) / 256, 256, 0, stream>>>(ei, ei + E, cnt, slist, E, ET);
  k_aggx<<<(N + 3) / 4, 256, 0, stream>>>(x, vbuf, slist, cnt, Yb, N);
  k_gi2<<<dim3((N + 63) / 64, 12), 128, 0, stream>>>(Yb, WW, gib, N);
  k_rec<<<(N + 3) / 4, 256, 0, stream>>>((const unsigned short*)gib, w_hh,
                                         b_hh, p1w, p1b, p2w, p2b,
                                         (float*)d_out, N);
}

// Round 13
// 92.160 us; speedup vs baseline: 3.9918x; 1.0801x over previous
//
#include <hip/hip_runtime.h>
#include <math.h>

#define HEADS 3
#define C_OUT 384
#define GAT_IN 24
#define HID 32
#define TSTEPS 12
#define NEG_SLOPE 0.2f
#define CAPW 64        // per-wave cached edges in k_aggx
#define SLOTS 96       // fixed slist stride per dst (P(deg>=96) ~ 1e-30)

typedef __attribute__((ext_vector_type(8))) short bf16x8;
typedef __attribute__((ext_vector_type(4))) float f32x4;

__device__ __forceinline__ float sigm(float x) {
  return 1.f / (1.f + __expf(-x));
}
__device__ __forceinline__ float tanh_fast(float x) {
  return 2.f / (1.f + __expf(-2.f * x)) - 1.f;
}
__device__ __forceinline__ unsigned short f2bf(float x) {
  unsigned int u = __float_as_uint(x);
  unsigned int r = u + 0x7fffu + ((u >> 16) & 1u);
  return (unsigned short)(r >> 16);
}
__device__ __forceinline__ float bf2f(unsigned short u) {
  return __uint_as_float((unsigned int)u << 16);
}
__device__ __forceinline__ float lrelu(float x) {
  return x >= 0.f ? x : NEG_SLOPE * x;
}

// ---------------- K_const: WWb/biasb fold + prep + cnt zero ----------------
// fold: WWb[t][k=h*24+j][g] (bf16) = sum_c lin_w[(h*384+t*32+c)*24+j]/3*wih[g][c]
//       biasb[t][g] = sum_c gat_bias[t*32+c]*wih[g][c] + bih[g]
__global__ __launch_bounds__(96) void k_const(const float* __restrict__ lin_w,
                                              const float* __restrict__ gat_bias,
                                              const float* __restrict__ wih,
                                              const float* __restrict__ bih,
                                              const float* __restrict__ att_src,
                                              const float* __restrict__ att_dst,
                                              unsigned short* __restrict__ WWb,
                                              float* __restrict__ biasb,
                                              float* __restrict__ vbuf,
                                              int* __restrict__ cnt, int N) {
  int b = blockIdx.x;
  if (b < 876) {  // fold
    int t = b / 73, k = b % 73;
    int g = threadIdx.x;  // 0..95
    __shared__ float s_w[32];
    if (g < 32) {
      if (k < 72) {
        int h = k / 24, j = k % 24;
        s_w[g] = lin_w[(size_t)(h * C_OUT + t * 32 + g) * GAT_IN + j] * (1.f / 3.f);
      } else {
        s_w[g] = gat_bias[t * 32 + g];
      }
    }
    __syncthreads();
    const float* wrow = wih + (size_t)g * 32;
    float acc = 0.f;
#pragma unroll
    for (int c = 0; c < 32; ++c) acc += s_w[c] * wrow[c];
    if (k < 72) {
      WWb[((size_t)t * 72 + k) * 96 + g] = f2bf(acc);
    } else {
      biasb[t * 96 + g] = acc + bih[g];
    }
  } else if (b < 948) {  // prep (single wave)
    int bb = b - 876;  // 0..71
    int h = bb / 24, j = bb % 24;
    int lane = threadIdx.x;
    if (lane >= 64) return;
    float as = 0.f, ad = 0.f;
    for (int c = lane; c < C_OUT; c += 64) {
      float wv = lin_w[(size_t)(h * C_OUT + c) * GAT_IN + j];
      as += att_src[h * C_OUT + c] * wv;
      ad += att_dst[h * C_OUT + c] * wv;
    }
#pragma unroll
    for (int off = 32; off >= 1; off >>= 1) {
      as += __shfl_xor(as, off, 64);
      ad += __shfl_xor(ad, off, 64);
    }
    if (lane == 0) {
      vbuf[h * 24 + j] = as;
      vbuf[72 + h * 24 + j] = ad;
    }
  } else {  // zero cnt
    int i = (b - 948) * 96 + threadIdx.x;
    if (i < N) cnt[i] = 0;
  }
}

// ---------------- K_place: bucket edges by dst, fixed stride ---------------
__global__ void k_place(const int* __restrict__ esrc,
                        const int* __restrict__ edst, int* __restrict__ cnt,
                        int* __restrict__ slist, int E, int ET) {
  int e = blockIdx.x * blockDim.x + threadIdx.x;
  if (e >= ET) return;
  int d, s;
  if (e < E) { d = edst[e]; s = esrc[e]; }
  else { d = e - E; s = e - E; }
  int pos = atomicAdd(&cnt[d], 1);
  if (pos < SLOTS) slist[(size_t)d * SLOTS + pos] = s;
}

// ---------------- K6: logits + softmax + xf-space aggregation --------------
// One dst node per 64-lane wave, 4 waves/block. Y output now bf16.
__global__ __launch_bounds__(256) void k_aggx(
    const float* __restrict__ xf, const float* __restrict__ vbuf,
    const int* __restrict__ slist, const int* __restrict__ cnt,
    unsigned short* __restrict__ Yb, int N) {
  __shared__ float s_v[144];
  __shared__ float s_w[4][CAPW][3];
  __shared__ float s_x[4][CAPW][25];  // cached xf rows (pad 25: conflict-free)
  int tid = threadIdx.x, lane = tid & 63, wv = tid >> 6;
  if (tid < 144) s_v[tid] = vbuf[tid];
  __syncthreads();  // before any wave can exit
  int n = blockIdx.x * 4 + wv;
  if (n >= N) return;  // per-wave exit; no barriers below

  int deg = min(cnt[n], SLOTS);

  // a_dst[n][h] = xf[n] . v_dst[h] : lanes 0..23 hold xf, xor-reduce
  float xl = (lane < 24) ? xf[(size_t)n * 24 + lane] : 0.f;
  float ad0, ad1, ad2;
  {
    float p0 = (lane < 24) ? xl * s_v[72 + lane] : 0.f;
    float p1 = (lane < 24) ? xl * s_v[96 + lane] : 0.f;
    float p2 = (lane < 24) ? xl * s_v[120 + lane] : 0.f;
#pragma unroll
    for (int off = 32; off >= 1; off >>= 1) {
      p0 += __shfl_xor(p0, off, 64);
      p1 += __shfl_xor(p1, off, 64);
      p2 += __shfl_xor(p2, off, 64);
    }
    ad0 = p0; ad1 = p1; ad2 = p2;
  }

  // pass A: per-edge logits from xf, exp, sum; rows+weights cached in LDS
  float t0 = 0.f, t1 = 0.f, t2 = 0.f;
  for (int i = lane; i < deg; i += 64) {
    int s = slist[(size_t)n * SLOTS + i];
    const float4* xr = (const float4*)(xf + (size_t)s * 24);
    float xs[24];
#pragma unroll
    for (int q = 0; q < 6; ++q) {
      float4 v = xr[q];
      xs[4 * q] = v.x; xs[4 * q + 1] = v.y;
      xs[4 * q + 2] = v.z; xs[4 * q + 3] = v.w;
    }
    float as0 = 0.f, as1 = 0.f, as2 = 0.f;
#pragma unroll
    for (int j = 0; j < 24; ++j) {
      float v = xs[j];
      as0 += v * s_v[j];
      as1 += v * s_v[24 + j];
      as2 += v * s_v[48 + j];
    }
    float e0 = __expf(lrelu(as0 + ad0));
    float e1 = __expf(lrelu(as1 + ad1));
    float e2 = __expf(lrelu(as2 + ad2));
    if (i < CAPW) {
      s_w[wv][i][0] = e0; s_w[wv][i][1] = e1; s_w[wv][i][2] = e2;
#pragma unroll
      for (int j = 0; j < 24; ++j) s_x[wv][i][j] = xs[j];
    }
    t0 += e0; t1 += e1; t2 += e2;
  }
#pragma unroll
  for (int off = 32; off >= 1; off >>= 1) {
    t0 += __shfl_xor(t0, off, 64);
    t1 += __shfl_xor(t1, off, 64);
    t2 += __shfl_xor(t2, off, 64);
  }
  float inv0 = 1.f / t0, inv1 = 1.f / t1, inv2 = 1.f / t2;

  // pass B: 2 edge-slots x 24 active channel-lanes; all reads from LDS
  int eg = lane >> 5;   // edge slot 0/1
  int c = lane & 31;    // channel (active c<24)
  float acc0 = 0.f, acc1 = 0.f, acc2 = 0.f;
  if (deg <= CAPW) {
    int cc = (c < 24) ? c : 0;
    float cmask = (c < 24) ? 1.f : 0.f;
#pragma unroll 2
    for (int i = eg; i < deg; i += 2) {
      float w0 = s_w[wv][i][0] * inv0;
      float w1 = s_w[wv][i][1] * inv1;
      float w2 = s_w[wv][i][2] * inv2;
      float xv = s_x[wv][i][cc] * cmask;
      acc0 += w0 * xv; acc1 += w1 * xv; acc2 += w2 * xv;
    }
  } else {
    for (int i = eg; i < deg; i += 2) {
      int s = slist[(size_t)n * SLOTS + i];
      float as0 = 0.f, as1 = 0.f, as2 = 0.f;
      const float* xr = xf + (size_t)s * 24;
#pragma unroll
      for (int j = 0; j < 24; ++j) {
        float v = xr[j];
        as0 += v * s_v[j];
        as1 += v * s_v[24 + j];
        as2 += v * s_v[48 + j];
      }
      float w0 = __expf(lrelu(as0 + ad0)) * inv0;
      float w1 = __expf(lrelu(as1 + ad1)) * inv1;
      float w2 = __expf(lrelu(as2 + ad2)) * inv2;
      float xv = (c < 24) ? xf[(size_t)s * 24 + c] : 0.f;
      acc0 += w0 * xv; acc1 += w1 * xv; acc2 += w2 * xv;
    }
  }
  acc0 += __shfl_xor(acc0, 32, 64);
  acc1 += __shfl_xor(acc1, 32, 64);
  acc2 += __shfl_xor(acc2, 32, 64);
  if (lane < 24) {
    unsigned short* yr = Yb + (size_t)n * 72;
    yr[lane] = f2bf(acc0);
    yr[24 + lane] = f2bf(acc1);
    yr[48 + lane] = f2bf(acc2);
  }
}

// ---------------- K_gmm: gi(bf16) = Y(bf16) @ WWb[t](bf16) + biasb[t] ------
// MFMA 16x16x32 bf16. Block: 256 thr = 4 waves; M=64 nodes, N=96 (one t),
// K=72 zero-padded to 96 (3 chunks). A-frags hoisted across the 6 N-tiles.
// Frag layout (guide §3, HW-verified): A: lane l -> A[l&15][(l>>4)*8+j];
// B: lane l -> B[(l>>4)*8+j][l&15]; D: col=l&15, row=(l>>4)*4+reg.
__global__ __launch_bounds__(256) void k_gmm(
    const unsigned short* __restrict__ Yb,
    const unsigned short* __restrict__ WWb,
    const float* __restrict__ biasb, unsigned short* __restrict__ gi, int N) {
  __shared__ short A_lds[64][104];  // row stride 208 B (16B mult)
  __shared__ short Bt[96][104];     // B transposed: Bt[g][k]
  __shared__ float s_bias[96];
  int tid = threadIdx.x;
  int m0 = blockIdx.x * 64;
  int t = blockIdx.y;
  if (tid < 96) s_bias[tid] = biasb[t * 96 + tid];
  // stage A: 64 rows x 36 uints (72 bf16)
  const unsigned int* Yu = (const unsigned int*)Yb;
  for (int u = tid; u < 64 * 36; u += 256) {
    int r = u / 36, c2 = u % 36;
    int rc = min(m0 + r, N - 1);
    *(unsigned int*)&A_lds[r][c2 * 2] = Yu[(size_t)rc * 36 + c2];
  }
  for (int u = tid; u < 64 * 16; u += 256) {  // zero pad k 72..103
    int r = u / 16, c2 = u % 16;
    *(unsigned int*)&A_lds[r][72 + c2 * 2] = 0;
  }
  // stage B transposed: WWb[t][k][g] -> Bt[g][k]
  const unsigned int* Wu = (const unsigned int*)(WWb + (size_t)t * 72 * 96);
  for (int u = tid; u < 72 * 48; u += 256) {
    int k = u / 48, g2 = u % 48;
    unsigned int v = Wu[(size_t)k * 48 + g2];
    Bt[2 * g2][k] = (short)(v & 0xffffu);
    Bt[2 * g2 + 1][k] = (short)(v >> 16);
  }
  for (int u = tid; u < 96 * 12; u += 256) {  // zero pad k 72..95
    int g = u / 12, c2 = u % 12;
    *(unsigned int*)&Bt[g][72 + c2 * 2] = 0;
  }
  __syncthreads();

  int w = tid >> 6, l = tid & 63;
  int mrow = w * 16 + (l & 15);
  int koff = (l >> 4) * 8;
  bf16x8 a0 = *(const bf16x8*)&A_lds[mrow][0 + koff];
  bf16x8 a1 = *(const bf16x8*)&A_lds[mrow][32 + koff];
  bf16x8 a2 = *(const bf16x8*)&A_lds[mrow][64 + koff];
  int rbase = m0 + w * 16 + (l >> 4) * 4;
#pragma unroll
  for (int nt = 0; nt < 6; ++nt) {
    int col = nt * 16 + (l & 15);
    bf16x8 b0 = *(const bf16x8*)&Bt[col][0 + koff];
    bf16x8 b1 = *(const bf16x8*)&Bt[col][32 + koff];
    bf16x8 b2 = *(const bf16x8*)&Bt[col][64 + koff];
    f32x4 acc = {0.f, 0.f, 0.f, 0.f};
    acc = __builtin_amdgcn_mfma_f32_16x16x32_bf16(a0, b0, acc, 0, 0, 0);
    acc = __builtin_amdgcn_mfma_f32_16x16x32_bf16(a1, b1, acc, 0, 0, 0);
    acc = __builtin_amdgcn_mfma_f32_16x16x32_bf16(a2, b2, acc, 0, 0, 0);
    float bs = s_bias[col];
#pragma unroll
    for (int rg = 0; rg < 4; ++rg) {
      int n = rbase + rg;
      if (n < N) gi[(size_t)n * 1152 + t * 96 + col] = f2bf(acc[rg] + bs);
    }
  }
}

// ---------------- K7b: GRU recurrence + projections ------------------------
__global__ __launch_bounds__(256, 4) void k_rec(
    const unsigned short* __restrict__ gi, const float* __restrict__ whh,
    const float* __restrict__ bhh, const float* __restrict__ p1w,
    const float* __restrict__ p1b, const float* __restrict__ p2w,
    const float* __restrict__ p2b, float* __restrict__ out, int N) {
  __shared__ float h_hist[4][13][36];
  __shared__ float s_o[4][12];
  int tid = threadIdx.x;
  int wv = tid >> 6;   // node slot 0..3
  int lane = tid & 63;
  int k = lane & 31;   // hidden unit
  int jh = lane >> 5;  // j-half: 0 -> h[0..15], 1 -> h[16..31]
  int node = blockIdx.x * 4 + wv;
  if (node >= N) return;  // per-wave exit; no barriers below

  const float4* pr = (const float4*)(whh + (size_t)k * HID + jh * 16);
  const float4* pz = (const float4*)(whh + (size_t)(HID + k) * HID + jh * 16);
  const float4* pn = (const float4*)(whh + (size_t)(2 * HID + k) * HID + jh * 16);
  float4 wr0 = pr[0], wr1 = pr[1], wr2 = pr[2], wr3 = pr[3];
  float4 wz0 = pz[0], wz1 = pz[1], wz2 = pz[2], wz3 = pz[3];
  float4 wn0 = pn[0], wn1 = pn[1], wn2 = pn[2], wn3 = pn[3];
  float bhr = bhh[k], bhz = bhh[HID + k], bhn = bhh[2 * HID + k];

  if (jh == 0) h_hist[wv][0][k] = 0.f;
  float h = 0.f;
  const unsigned short* gbase = gi + (size_t)node * TSTEPS * 96;
  float gr = bf2f(gbase[k]), gz = bf2f(gbase[32 + k]), gn = bf2f(gbase[64 + k]);

  for (int t = 0; t < TSTEPS; ++t) {
    float gr1 = 0.f, gz1 = 0.f, gn1 = 0.f;
    if (t + 1 < TSTEPS) {
      const unsigned short* pa = gbase + (t + 1) * 96;
      gr1 = bf2f(pa[k]); gz1 = bf2f(pa[32 + k]); gn1 = bf2f(pa[64 + k]);
    }
    const float* hh = &h_hist[wv][t][jh * 16];
    float4 h0 = *(const float4*)(hh);
    float4 h1 = *(const float4*)(hh + 4);
    float4 h2 = *(const float4*)(hh + 8);
    float4 h3 = *(const float4*)(hh + 12);
    float ar = wr0.x * h0.x + wr0.y * h0.y + wr0.z * h0.z + wr0.w * h0.w +
               wr1.x * h1.x + wr1.y * h1.y + wr1.z * h1.z + wr1.w * h1.w +
               wr2.x * h2.x + wr2.y * h2.y + wr2.z * h2.z + wr2.w * h2.w +
               wr3.x * h3.x + wr3.y * h3.y + wr3.z * h3.z + wr3.w * h3.w;
    float az = wz0.x * h0.x + wz0.y * h0.y + wz0.z * h0.z + wz0.w * h0.w +
               wz1.x * h1.x + wz1.y * h1.y + wz1.z * h1.z + wz1.w * h1.w +
               wz2.x * h2.x + wz2.y * h2.y + wz2.z * h2.z + wz2.w * h2.w +
               wz3.x * h3.x + wz3.y * h3.y + wz3.z * h3.z + wz3.w * h3.w;
    float an = wn0.x * h0.x + wn0.y * h0.y + wn0.z * h0.z + wn0.w * h0.w +
               wn1.x * h1.x + wn1.y * h1.y + wn1.z * h1.z + wn1.w * h1.w +
               wn2.x * h2.x + wn2.y * h2.y + wn2.z * h2.z + wn2.w * h2.w +
               wn3.x * h3.x + wn3.y * h3.y + wn3.z * h3.z + wn3.w * h3.w;
    ar += __shfl_xor(ar, 32, 64);
    az += __shfl_xor(az, 32, 64);
    an += __shfl_xor(an, 32, 64);
    float r = sigm(gr + ar + bhr);
    float z = sigm(gz + az + bhz);
    float nn = tanh_fast(gn + r * (an + bhn));
    h = (1.f - z) * nn + z * h;
    if (jh == 0) h_hist[wv][t + 1][k] = h;
    gr = gr1; gz = gz1; gn = gn1;
  }
  if (jh == 0 && k < TSTEPS) {
    float o = p1b[0];
#pragma unroll
    for (int kk = 0; kk < HID; ++kk) o += h_hist[wv][k + 1][kk] * p1w[kk];
    s_o[wv][k] = o;
  }
  if (jh == 0 && k < TSTEPS) {
    float acc = p2b[k];
#pragma unroll
    for (int s2 = 0; s2 < TSTEPS; ++s2)
      acc += p2w[k * TSTEPS + s2] * s_o[wv][s2];
    out[(size_t)node * TSTEPS + k] = acc;
  }
}

// ---------------------------------------------------------------------------
extern "C" void kernel_launch(void* const* d_in, const int* in_sizes, int n_in,
                              void* d_out, int out_size, void* d_ws,
                              size_t ws_size, hipStream_t stream) {
  const float* x = (const float*)d_in[0];
  const int* ei = (const int*)d_in[1];
  const float* lin_w = (const float*)d_in[2];
  const float* att_src = (const float*)d_in[3];
  const float* att_dst = (const float*)d_in[4];
  const float* gat_bias = (const float*)d_in[5];
  const float* w_ih = (const float*)d_in[6];
  const float* w_hh = (const float*)d_in[7];
  const float* b_ih = (const float*)d_in[8];
  const float* b_hh = (const float*)d_in[9];
  const float* p1w = (const float*)d_in[10];
  const float* p1b = (const float*)d_in[11];
  const float* p2w = (const float*)d_in[12];
  const float* p2b = (const float*)d_in[13];

  int N = in_sizes[0] / GAT_IN;  // 10000
  int E = in_sizes[1] / 2;       // 160000
  int ET = E + N;

  size_t off = 0;
  char* base = (char*)d_ws;
  auto alloc = [&](size_t bytes) {
    void* p = base + off;
    off += (bytes + 255) & ~(size_t)255;
    return p;
  };
  unsigned short* gib = (unsigned short*)alloc((size_t)N * 1152 * 2);  // bf16 gi
  unsigned short* Yb = (unsigned short*)alloc((size_t)N * 72 * 2);     // bf16 Y
  unsigned short* WWb = (unsigned short*)alloc((size_t)12 * 72 * 96 * 2);
  float* biasb = (float*)alloc((size_t)12 * 96 * 4);
  float* vbuf = (float*)alloc(144 * 4);
  int* cnt = (int*)alloc((size_t)N * 4);
  int* slist = (int*)alloc((size_t)N * SLOTS * 4);
  (void)ws_size; (void)n_in; (void)out_size;

  int zero_blocks = (N + 95) / 96;  // 105
  k_const<<<948 + zero_blocks, 96, 0, stream>>>(lin_w, gat_bias, w_ih, b_ih,
                                                att_src, att_dst, WWb, biasb,
                                                vbuf, cnt, N);
  k_place<<<(ET + 255) / 256, 256, 0, stream>>>(ei, ei + E, cnt, slist, E, ET);
  k_aggx<<<(N + 3) / 4, 256, 0, stream>>>(x, vbuf, slist, cnt, Yb, N);
  k_gmm<<<dim3((N + 63) / 64, 12), 256, 0, stream>>>(Yb, WWb, biasb, gib, N);
  k_rec<<<(N + 3) / 4, 256, 0, stream>>>(gib, w_hh, b_hh, p1w, p1b, p2w, p2b,
                                         (float*)d_out, N);
}

// Round 14
// 86.170 us; speedup vs baseline: 4.2692x; 1.0695x over previous
//
#include <hip/hip_runtime.h>
#include <math.h>

#define HEADS 3
#define C_OUT 384
#define GAT_IN 24
#define HID 32
#define TSTEPS 12
#define NEG_SLOPE 0.2f
#define CAPW 64        // per-wave cached edges in k_aggx
#define SLOTS 96       // fixed slist stride per dst (P(deg>=96) ~ 1e-30)

typedef __attribute__((ext_vector_type(8))) short bf16x8;
typedef __attribute__((ext_vector_type(4))) float f32x4;

__device__ __forceinline__ float sigm(float x) {
  return 1.f / (1.f + __expf(-x));
}
__device__ __forceinline__ float tanh_fast(float x) {
  return 2.f / (1.f + __expf(-2.f * x)) - 1.f;
}
__device__ __forceinline__ unsigned short f2bf(float x) {
  unsigned int u = __float_as_uint(x);
  unsigned int r = u + 0x7fffu + ((u >> 16) & 1u);
  return (unsigned short)(r >> 16);
}
__device__ __forceinline__ float bf2f(unsigned short u) {
  return __uint_as_float((unsigned int)u << 16);
}
__device__ __forceinline__ float lrelu(float x) {
  return x >= 0.f ? x : NEG_SLOPE * x;
}

// ---------------- K_const: WWt/biasb fold + prep + cnt zero ----------------
// WWt[t][g][k] (bf16, k zero-padded to 96):
//   WWt[t][g][k=h*24+j] = sum_c lin_w[(h*384+t*32+c)*24+j]/3 * wih[g][c]
// biasb[t][g] = sum_c gat_bias[t*32+c]*wih[g][c] + bih[g]
__global__ __launch_bounds__(96) void k_const(const float* __restrict__ lin_w,
                                              const float* __restrict__ gat_bias,
                                              const float* __restrict__ wih,
                                              const float* __restrict__ bih,
                                              const float* __restrict__ att_src,
                                              const float* __restrict__ att_dst,
                                              unsigned short* __restrict__ WWt,
                                              float* __restrict__ biasb,
                                              float* __restrict__ vbuf,
                                              int* __restrict__ cnt, int N) {
  int b = blockIdx.x;
  if (b < 876) {  // fold
    int t = b / 73, k = b % 73;
    int g = threadIdx.x;  // 0..95
    __shared__ float s_w[32];
    if (g < 32) {
      if (k < 72) {
        int h = k / 24, j = k % 24;
        s_w[g] = lin_w[(size_t)(h * C_OUT + t * 32 + g) * GAT_IN + j] * (1.f / 3.f);
      } else {
        s_w[g] = gat_bias[t * 32 + g];
      }
    }
    __syncthreads();
    const float* wrow = wih + (size_t)g * 32;
    float acc = 0.f;
#pragma unroll
    for (int c = 0; c < 32; ++c) acc += s_w[c] * wrow[c];
    if (k < 72) {
      WWt[((size_t)t * 96 + g) * 96 + k] = f2bf(acc);
      if (k < 24) WWt[((size_t)t * 96 + g) * 96 + 72 + k] = 0;  // zero pad
    } else {
      biasb[t * 96 + g] = acc + bih[g];
    }
  } else if (b < 948) {  // prep (single wave)
    int bb = b - 876;  // 0..71
    int h = bb / 24, j = bb % 24;
    int lane = threadIdx.x;
    if (lane >= 64) return;
    float as = 0.f, ad = 0.f;
    for (int c = lane; c < C_OUT; c += 64) {
      float wv = lin_w[(size_t)(h * C_OUT + c) * GAT_IN + j];
      as += att_src[h * C_OUT + c] * wv;
      ad += att_dst[h * C_OUT + c] * wv;
    }
#pragma unroll
    for (int off = 32; off >= 1; off >>= 1) {
      as += __shfl_xor(as, off, 64);
      ad += __shfl_xor(ad, off, 64);
    }
    if (lane == 0) {
      vbuf[h * 24 + j] = as;
      vbuf[72 + h * 24 + j] = ad;
    }
  } else {  // zero cnt
    int i = (b - 948) * 96 + threadIdx.x;
    if (i < N) cnt[i] = 0;
  }
}

// ---------------- K_place: bucket edges by dst, fixed stride ---------------
__global__ void k_place(const int* __restrict__ esrc,
                        const int* __restrict__ edst, int* __restrict__ cnt,
                        int* __restrict__ slist, int E, int ET) {
  int e = blockIdx.x * blockDim.x + threadIdx.x;
  if (e >= ET) return;
  int d, s;
  if (e < E) { d = edst[e]; s = esrc[e]; }
  else { d = e - E; s = e - E; }
  int pos = atomicAdd(&cnt[d], 1);
  if (pos < SLOTS) slist[(size_t)d * SLOTS + pos] = s;
}

// ---------------- K6: logits + softmax + xf-space aggregation --------------
// One dst node per 64-lane wave, 4 waves/block. s_x cached as bf16 -> 17 KB
// LDS -> ~9 blocks/CU occupancy for this latency-bound gather kernel.
__global__ __launch_bounds__(256) void k_aggx(
    const float* __restrict__ xf, const float* __restrict__ vbuf,
    const int* __restrict__ slist, const int* __restrict__ cnt,
    unsigned short* __restrict__ Yb, int N) {
  __shared__ float s_v[144];
  __shared__ float s_w[4][CAPW][3];
  __shared__ unsigned short s_xb[4][CAPW][26];  // bf16 xf rows
  int tid = threadIdx.x, lane = tid & 63, wv = tid >> 6;
  if (tid < 144) s_v[tid] = vbuf[tid];
  __syncthreads();  // before any wave can exit
  int n = blockIdx.x * 4 + wv;
  if (n >= N) return;  // per-wave exit; no barriers below

  int deg = min(cnt[n], SLOTS);

  // a_dst[n][h] = xf[n] . v_dst[h] : lanes 0..23 hold xf, xor-reduce
  float xl = (lane < 24) ? xf[(size_t)n * 24 + lane] : 0.f;
  float ad0, ad1, ad2;
  {
    float p0 = (lane < 24) ? xl * s_v[72 + lane] : 0.f;
    float p1 = (lane < 24) ? xl * s_v[96 + lane] : 0.f;
    float p2 = (lane < 24) ? xl * s_v[120 + lane] : 0.f;
#pragma unroll
    for (int off = 32; off >= 1; off >>= 1) {
      p0 += __shfl_xor(p0, off, 64);
      p1 += __shfl_xor(p1, off, 64);
      p2 += __shfl_xor(p2, off, 64);
    }
    ad0 = p0; ad1 = p1; ad2 = p2;
  }

  // pass A: per-edge logits from xf, exp, sum; rows+weights cached in LDS
  float t0 = 0.f, t1 = 0.f, t2 = 0.f;
  for (int i = lane; i < deg; i += 64) {
    int s = slist[(size_t)n * SLOTS + i];
    const float4* xr = (const float4*)(xf + (size_t)s * 24);
    float xs[24];
#pragma unroll
    for (int q = 0; q < 6; ++q) {
      float4 v = xr[q];
      xs[4 * q] = v.x; xs[4 * q + 1] = v.y;
      xs[4 * q + 2] = v.z; xs[4 * q + 3] = v.w;
    }
    float as0 = 0.f, as1 = 0.f, as2 = 0.f;
#pragma unroll
    for (int j = 0; j < 24; ++j) {
      float v = xs[j];
      as0 += v * s_v[j];
      as1 += v * s_v[24 + j];
      as2 += v * s_v[48 + j];
    }
    float e0 = __expf(lrelu(as0 + ad0));
    float e1 = __expf(lrelu(as1 + ad1));
    float e2 = __expf(lrelu(as2 + ad2));
    if (i < CAPW) {
      s_w[wv][i][0] = e0; s_w[wv][i][1] = e1; s_w[wv][i][2] = e2;
#pragma unroll
      for (int j = 0; j < 24; ++j) s_xb[wv][i][j] = f2bf(xs[j]);
    }
    t0 += e0; t1 += e1; t2 += e2;
  }
#pragma unroll
  for (int off = 32; off >= 1; off >>= 1) {
    t0 += __shfl_xor(t0, off, 64);
    t1 += __shfl_xor(t1, off, 64);
    t2 += __shfl_xor(t2, off, 64);
  }
  float inv0 = 1.f / t0, inv1 = 1.f / t1, inv2 = 1.f / t2;

  // pass B: 2 edge-slots x 24 active channel-lanes; all reads from LDS
  int eg = lane >> 5;   // edge slot 0/1
  int c = lane & 31;    // channel (active c<24)
  float acc0 = 0.f, acc1 = 0.f, acc2 = 0.f;
  if (deg <= CAPW) {
    int cc = (c < 24) ? c : 0;
    float cmask = (c < 24) ? 1.f : 0.f;
#pragma unroll 2
    for (int i = eg; i < deg; i += 2) {
      float w0 = s_w[wv][i][0] * inv0;
      float w1 = s_w[wv][i][1] * inv1;
      float w2 = s_w[wv][i][2] * inv2;
      float xv = bf2f(s_xb[wv][i][cc]) * cmask;
      acc0 += w0 * xv; acc1 += w1 * xv; acc2 += w2 * xv;
    }
  } else {
    for (int i = eg; i < deg; i += 2) {
      int s = slist[(size_t)n * SLOTS + i];
      float as0 = 0.f, as1 = 0.f, as2 = 0.f;
      const float* xr = xf + (size_t)s * 24;
#pragma unroll
      for (int j = 0; j < 24; ++j) {
        float v = xr[j];
        as0 += v * s_v[j];
        as1 += v * s_v[24 + j];
        as2 += v * s_v[48 + j];
      }
      float w0 = __expf(lrelu(as0 + ad0)) * inv0;
      float w1 = __expf(lrelu(as1 + ad1)) * inv1;
      float w2 = __expf(lrelu(as2 + ad2)) * inv2;
      float xv = (c < 24) ? xf[(size_t)s * 24 + c] : 0.f;
      acc0 += w0 * xv; acc1 += w1 * xv; acc2 += w2 * xv;
    }
  }
  acc0 += __shfl_xor(acc0, 32, 64);
  acc1 += __shfl_xor(acc1, 32, 64);
  acc2 += __shfl_xor(acc2, 32, 64);
  if (lane < 24) {
    unsigned short* yr = Yb + (size_t)n * 72;
    yr[lane] = f2bf(acc0);
    yr[24 + lane] = f2bf(acc1);
    yr[48 + lane] = f2bf(acc2);
  }
}

// ---------------- K_gmr: fused gi-GEMM (MFMA) + GRU recurrence -------------
// Block = 16 nodes, 256 thr (4 waves). Phase 1: wave w computes gi for
// t = 3w..3w+2 via mfma_16x16x32_bf16 into gi_lds (gi never hits global).
// Phase 2: each wave runs 4 nodes' GRU from gi_lds; p1 projection computed
// on the fly per step (no h history).
__global__ __launch_bounds__(256, 2) void k_gmr(
    const unsigned short* __restrict__ Yb,
    const unsigned short* __restrict__ WWt, const float* __restrict__ biasb,
    const float* __restrict__ whh, const float* __restrict__ bhh,
    const float* __restrict__ p1w, const float* __restrict__ p1b,
    const float* __restrict__ p2w, const float* __restrict__ p2b,
    float* __restrict__ out, int N) {
  __shared__ short A_lds[16][104];            // Y rows, K padded to 96
  __shared__ unsigned short gi_lds[12][16][96];
  __shared__ float s_bias[12][96];
  __shared__ float h_buf[4][36];
  __shared__ float s_o[16][12];
  int tid = threadIdx.x;
  int m0 = blockIdx.x * 16;

  // stage A: 16 rows x 36 uints (72 bf16) + zero pad k 72..103
  const unsigned int* Yu = (const unsigned int*)Yb;
  for (int u = tid; u < 16 * 36; u += 256) {
    int r = u / 36, c2 = u % 36;
    int rc = min(m0 + r, N - 1);
    *(unsigned int*)&A_lds[r][c2 * 2] = Yu[(size_t)rc * 36 + c2];
  }
  if (tid < 256) {
    int r = tid >> 4, c2 = tid & 15;
    *(unsigned int*)&A_lds[r][72 + c2 * 2] = 0;
  }
  for (int u = tid; u < 12 * 96; u += 256) s_bias[u / 96][u % 96] = biasb[u];
  __syncthreads();

  int l = tid & 63, wv = tid >> 6;
  // ---- phase 1: MFMA gi for this wave's 3 t-values ----
  {
    int mrow = l & 15;
    int koff = (l >> 4) * 8;
    bf16x8 a0 = *(const bf16x8*)&A_lds[mrow][koff];
    bf16x8 a1 = *(const bf16x8*)&A_lds[mrow][32 + koff];
    bf16x8 a2 = *(const bf16x8*)&A_lds[mrow][64 + koff];
    int rrow = (l >> 4) * 4;
#pragma unroll
    for (int q = 0; q < 3; ++q) {
      int tt = wv * 3 + q;
#pragma unroll
      for (int nt = 0; nt < 6; ++nt) {
        int col = nt * 16 + (l & 15);
        const unsigned short* bp = WWt + ((size_t)tt * 96 + col) * 96 + koff;
        bf16x8 b0 = *(const bf16x8*)&bp[0];
        bf16x8 b1 = *(const bf16x8*)&bp[32];
        bf16x8 b2 = *(const bf16x8*)&bp[64];
        f32x4 acc = {0.f, 0.f, 0.f, 0.f};
        acc = __builtin_amdgcn_mfma_f32_16x16x32_bf16(a0, b0, acc, 0, 0, 0);
        acc = __builtin_amdgcn_mfma_f32_16x16x32_bf16(a1, b1, acc, 0, 0, 0);
        acc = __builtin_amdgcn_mfma_f32_16x16x32_bf16(a2, b2, acc, 0, 0, 0);
        float bs = s_bias[tt][col];
#pragma unroll
        for (int rg = 0; rg < 4; ++rg)
          gi_lds[tt][rrow + rg][col] = f2bf(acc[rg] + bs);
      }
    }
  }
  __syncthreads();

  // ---- phase 2: GRU recurrence, 4 serial nodes per wave ----
  int k = l & 31, jh = l >> 5;
  const float4* pr = (const float4*)(whh + (size_t)k * HID + jh * 16);
  const float4* pz = (const float4*)(whh + (size_t)(HID + k) * HID + jh * 16);
  const float4* pn = (const float4*)(whh + (size_t)(2 * HID + k) * HID + jh * 16);
  float4 wr0 = pr[0], wr1 = pr[1], wr2 = pr[2], wr3 = pr[3];
  float4 wz0 = pz[0], wz1 = pz[1], wz2 = pz[2], wz3 = pz[3];
  float4 wn0 = pn[0], wn1 = pn[1], wn2 = pn[2], wn3 = pn[3];
  float bhr = bhh[k], bhz = bhh[HID + k], bhn = bhh[2 * HID + k];
  float p1k = p1w[k];
  float p1b0 = p1b[0];

  for (int i = 0; i < 4; ++i) {
    int nl = wv * 4 + i;
    int node = m0 + nl;
    if (node >= N) break;  // wave-uniform
    if (jh == 0) h_buf[wv][k] = 0.f;
    float h = 0.f;
    float gr = bf2f(gi_lds[0][nl][k]);
    float gz = bf2f(gi_lds[0][nl][32 + k]);
    float gn = bf2f(gi_lds[0][nl][64 + k]);
    for (int t = 0; t < TSTEPS; ++t) {
      float gr1 = 0.f, gz1 = 0.f, gn1 = 0.f;
      if (t + 1 < TSTEPS) {
        gr1 = bf2f(gi_lds[t + 1][nl][k]);
        gz1 = bf2f(gi_lds[t + 1][nl][32 + k]);
        gn1 = bf2f(gi_lds[t + 1][nl][64 + k]);
      }
      const float* hh = &h_buf[wv][jh * 16];
      float4 h0 = *(const float4*)(hh);
      float4 h1 = *(const float4*)(hh + 4);
      float4 h2 = *(const float4*)(hh + 8);
      float4 h3 = *(const float4*)(hh + 12);
      float ar = wr0.x * h0.x + wr0.y * h0.y + wr0.z * h0.z + wr0.w * h0.w +
                 wr1.x * h1.x + wr1.y * h1.y + wr1.z * h1.z + wr1.w * h1.w +
                 wr2.x * h2.x + wr2.y * h2.y + wr2.z * h2.z + wr2.w * h2.w +
                 wr3.x * h3.x + wr3.y * h3.y + wr3.z * h3.z + wr3.w * h3.w;
      float az = wz0.x * h0.x + wz0.y * h0.y + wz0.z * h0.z + wz0.w * h0.w +
                 wz1.x * h1.x + wz1.y * h1.y + wz1.z * h1.z + wz1.w * h1.w +
                 wz2.x * h2.x + wz2.y * h2.y + wz2.z * h2.z + wz2.w * h2.w +
                 wz3.x * h3.x + wz3.y * h3.y + wz3.z * h3.z + wz3.w * h3.w;
      float an = wn0.x * h0.x + wn0.y * h0.y + wn0.z * h0.z + wn0.w * h0.w +
                 wn1.x * h1.x + wn1.y * h1.y + wn1.z * h1.z + wn1.w * h1.w +
                 wn2.x * h2.x + wn2.y * h2.y + wn2.z * h2.z + wn2.w * h2.w +
                 wn3.x * h3.x + wn3.y * h3.y + wn3.z * h3.z + wn3.w * h3.w;
      ar += __shfl_xor(ar, 32, 64);
      az += __shfl_xor(az, 32, 64);
      an += __shfl_xor(an, 32, 64);
      float r = sigm(gr + ar + bhr);
      float z = sigm(gz + az + bhz);
      float nn = tanh_fast(gn + r * (an + bhn));
      h = (1.f - z) * nn + z * h;
      if (jh == 0) h_buf[wv][k] = h;
      // on-the-fly p1 projection: o_t = sum_k p1w[k]*h_t[k] + p1b
      float po = p1k * h;
#pragma unroll
      for (int off = 16; off >= 1; off >>= 1) po += __shfl_xor(po, off, 64);
      if (l == 0) s_o[nl][t] = po + p1b0;
      gr = gr1; gz = gz1; gn = gn1;
    }
    if (l < TSTEPS) {
      float acc = p2b[l];
#pragma unroll
      for (int s2 = 0; s2 < TSTEPS; ++s2)
        acc += p2w[l * TSTEPS + s2] * s_o[nl][s2];
      out[(size_t)node * TSTEPS + l] = acc;
    }
  }
}

// ---------------------------------------------------------------------------
extern "C" void kernel_launch(void* const* d_in, const int* in_sizes, int n_in,
                              void* d_out, int out_size, void* d_ws,
                              size_t ws_size, hipStream_t stream) {
  const float* x = (const float*)d_in[0];
  const int* ei = (const int*)d_in[1];
  const float* lin_w = (const float*)d_in[2];
  const float* att_src = (const float*)d_in[3];
  const float* att_dst = (const float*)d_in[4];
  const float* gat_bias = (const float*)d_in[5];
  const float* w_ih = (const float*)d_in[6];
  const float* w_hh = (const float*)d_in[7];
  const float* b_ih = (const float*)d_in[8];
  const float* b_hh = (const float*)d_in[9];
  const float* p1w = (const float*)d_in[10];
  const float* p1b = (const float*)d_in[11];
  const float* p2w = (const float*)d_in[12];
  const float* p2b = (const float*)d_in[13];

  int N = in_sizes[0] / GAT_IN;  // 10000
  int E = in_sizes[1] / 2;       // 160000
  int ET = E + N;

  size_t off = 0;
  char* base = (char*)d_ws;
  auto alloc = [&](size_t bytes) {
    void* p = base + off;
    off += (bytes + 255) & ~(size_t)255;
    return p;
  };
  unsigned short* Yb = (unsigned short*)alloc((size_t)N * 72 * 2);  // bf16 Y
  unsigned short* WWt = (unsigned short*)alloc((size_t)12 * 96 * 96 * 2);
  float* biasb = (float*)alloc((size_t)12 * 96 * 4);
  float* vbuf = (float*)alloc(144 * 4);
  int* cnt = (int*)alloc((size_t)N * 4);
  int* slist = (int*)alloc((size_t)N * SLOTS * 4);
  (void)ws_size; (void)n_in; (void)out_size;

  int zero_blocks = (N + 95) / 96;  // 105
  k_const<<<948 + zero_blocks, 96, 0, stream>>>(lin_w, gat_bias, w_ih, b_ih,
                                                att_src, att_dst, WWt, biasb,
                                                vbuf, cnt, N);
  k_place<<<(ET + 255) / 256, 256, 0, stream>>>(ei, ei + E, cnt, slist, E, ET);
  k_aggx<<<(N + 3) / 4, 256, 0, stream>>>(x, vbuf, slist, cnt, Yb, N);
  k_gmr<<<(N + 15) / 16, 256, 0, stream>>>(Yb, WWt, biasb, w_hh, b_hh, p1w,
                                           p1b, p2w, p2b, (float*)d_out, N);
}

// Round 15
// 81.956 us; speedup vs baseline: 4.4887x; 1.0514x over previous
//
#include <hip/hip_runtime.h>
#include <math.h>

#define HEADS 3
#define C_OUT 384
#define GAT_IN 24
#define HID 32
#define TSTEPS 12
#define NEG_SLOPE 0.2f
#define CAPW 64        // per-wave cached edges in k_aggx
#define SLOTS 96       // fixed slist stride per dst (P(deg>=96) ~ 1e-30)

typedef __attribute__((ext_vector_type(8))) short bf16x8;
typedef __attribute__((ext_vector_type(4))) float f32x4;

__device__ __forceinline__ float sigm(float x) {
  return 1.f / (1.f + __expf(-x));
}
__device__ __forceinline__ float tanh_fast(float x) {
  return 2.f / (1.f + __expf(-2.f * x)) - 1.f;
}
__device__ __forceinline__ unsigned short f2bf(float x) {
  unsigned int u = __float_as_uint(x);
  unsigned int r = u + 0x7fffu + ((u >> 16) & 1u);
  return (unsigned short)(r >> 16);
}
__device__ __forceinline__ float bf2f(unsigned short u) {
  return __uint_as_float((unsigned int)u << 16);
}
__device__ __forceinline__ float lrelu(float x) {
  return x >= 0.f ? x : NEG_SLOPE * x;
}

// ---------------- K_const: WWt/biasb fold + prep + cnt zero ----------------
__global__ __launch_bounds__(96) void k_const(const float* __restrict__ lin_w,
                                              const float* __restrict__ gat_bias,
                                              const float* __restrict__ wih,
                                              const float* __restrict__ bih,
                                              const float* __restrict__ att_src,
                                              const float* __restrict__ att_dst,
                                              unsigned short* __restrict__ WWt,
                                              float* __restrict__ biasb,
                                              float* __restrict__ vbuf,
                                              int* __restrict__ cnt, int N) {
  int b = blockIdx.x;
  if (b < 876) {  // fold
    int t = b / 73, k = b % 73;
    int g = threadIdx.x;  // 0..95
    __shared__ float s_w[32];
    if (g < 32) {
      if (k < 72) {
        int h = k / 24, j = k % 24;
        s_w[g] = lin_w[(size_t)(h * C_OUT + t * 32 + g) * GAT_IN + j] * (1.f / 3.f);
      } else {
        s_w[g] = gat_bias[t * 32 + g];
      }
    }
    __syncthreads();
    const float* wrow = wih + (size_t)g * 32;
    float acc = 0.f;
#pragma unroll
    for (int c = 0; c < 32; ++c) acc += s_w[c] * wrow[c];
    if (k < 72) {
      WWt[((size_t)t * 96 + g) * 96 + k] = f2bf(acc);
      if (k < 24) WWt[((size_t)t * 96 + g) * 96 + 72 + k] = 0;  // zero pad
    } else {
      biasb[t * 96 + g] = acc + bih[g];
    }
  } else if (b < 948) {  // prep (single wave)
    int bb = b - 876;  // 0..71
    int h = bb / 24, j = bb % 24;
    int lane = threadIdx.x;
    if (lane >= 64) return;
    float as = 0.f, ad = 0.f;
    for (int c = lane; c < C_OUT; c += 64) {
      float wv = lin_w[(size_t)(h * C_OUT + c) * GAT_IN + j];
      as += att_src[h * C_OUT + c] * wv;
      ad += att_dst[h * C_OUT + c] * wv;
    }
#pragma unroll
    for (int off = 32; off >= 1; off >>= 1) {
      as += __shfl_xor(as, off, 64);
      ad += __shfl_xor(ad, off, 64);
    }
    if (lane == 0) {
      vbuf[h * 24 + j] = as;
      vbuf[72 + h * 24 + j] = ad;
    }
  } else {  // zero cnt
    int i = (b - 948) * 96 + threadIdx.x;
    if (i < N) cnt[i] = 0;
  }
}

// ---------------- K_place: bucket edges by dst, fixed stride ---------------
__global__ void k_place(const int* __restrict__ esrc,
                        const int* __restrict__ edst, int* __restrict__ cnt,
                        int* __restrict__ slist, int E, int ET) {
  int e = blockIdx.x * blockDim.x + threadIdx.x;
  if (e >= ET) return;
  int d, s;
  if (e < E) { d = edst[e]; s = esrc[e]; }
  else { d = e - E; s = e - E; }
  int pos = atomicAdd(&cnt[d], 1);
  if (pos < SLOTS) slist[(size_t)d * SLOTS + pos] = s;
}

// ---------------- K6: logits + softmax + xf-space aggregation --------------
__global__ __launch_bounds__(256) void k_aggx(
    const float* __restrict__ xf, const float* __restrict__ vbuf,
    const int* __restrict__ slist, const int* __restrict__ cnt,
    unsigned short* __restrict__ Yb, int N) {
  __shared__ float s_v[144];
  __shared__ float s_w[4][CAPW][3];
  __shared__ unsigned short s_xb[4][CAPW][26];  // bf16 xf rows
  int tid = threadIdx.x, lane = tid & 63, wv = tid >> 6;
  if (tid < 144) s_v[tid] = vbuf[tid];
  __syncthreads();  // before any wave can exit
  int n = blockIdx.x * 4 + wv;
  if (n >= N) return;  // per-wave exit; no barriers below

  int deg = min(cnt[n], SLOTS);

  float xl = (lane < 24) ? xf[(size_t)n * 24 + lane] : 0.f;
  float ad0, ad1, ad2;
  {
    float p0 = (lane < 24) ? xl * s_v[72 + lane] : 0.f;
    float p1 = (lane < 24) ? xl * s_v[96 + lane] : 0.f;
    float p2 = (lane < 24) ? xl * s_v[120 + lane] : 0.f;
#pragma unroll
    for (int off = 32; off >= 1; off >>= 1) {
      p0 += __shfl_xor(p0, off, 64);
      p1 += __shfl_xor(p1, off, 64);
      p2 += __shfl_xor(p2, off, 64);
    }
    ad0 = p0; ad1 = p1; ad2 = p2;
  }

  float t0 = 0.f, t1 = 0.f, t2 = 0.f;
  for (int i = lane; i < deg; i += 64) {
    int s = slist[(size_t)n * SLOTS + i];
    const float4* xr = (const float4*)(xf + (size_t)s * 24);
    float xs[24];
#pragma unroll
    for (int q = 0; q < 6; ++q) {
      float4 v = xr[q];
      xs[4 * q] = v.x; xs[4 * q + 1] = v.y;
      xs[4 * q + 2] = v.z; xs[4 * q + 3] = v.w;
    }
    float as0 = 0.f, as1 = 0.f, as2 = 0.f;
#pragma unroll
    for (int j = 0; j < 24; ++j) {
      float v = xs[j];
      as0 += v * s_v[j];
      as1 += v * s_v[24 + j];
      as2 += v * s_v[48 + j];
    }
    float e0 = __expf(lrelu(as0 + ad0));
    float e1 = __expf(lrelu(as1 + ad1));
    float e2 = __expf(lrelu(as2 + ad2));
    if (i < CAPW) {
      s_w[wv][i][0] = e0; s_w[wv][i][1] = e1; s_w[wv][i][2] = e2;
#pragma unroll
      for (int j = 0; j < 24; ++j) s_xb[wv][i][j] = f2bf(xs[j]);
    }
    t0 += e0; t1 += e1; t2 += e2;
  }
#pragma unroll
  for (int off = 32; off >= 1; off >>= 1) {
    t0 += __shfl_xor(t0, off, 64);
    t1 += __shfl_xor(t1, off, 64);
    t2 += __shfl_xor(t2, off, 64);
  }
  float inv0 = 1.f / t0, inv1 = 1.f / t1, inv2 = 1.f / t2;

  int eg = lane >> 5;   // edge slot 0/1
  int c = lane & 31;    // channel (active c<24)
  float acc0 = 0.f, acc1 = 0.f, acc2 = 0.f;
  if (deg <= CAPW) {
    int cc = (c < 24) ? c : 0;
    float cmask = (c < 24) ? 1.f : 0.f;
#pragma unroll 2
    for (int i = eg; i < deg; i += 2) {
      float w0 = s_w[wv][i][0] * inv0;
      float w1 = s_w[wv][i][1] * inv1;
      float w2 = s_w[wv][i][2] * inv2;
      float xv = bf2f(s_xb[wv][i][cc]) * cmask;
      acc0 += w0 * xv; acc1 += w1 * xv; acc2 += w2 * xv;
    }
  } else {
    for (int i = eg; i < deg; i += 2) {
      int s = slist[(size_t)n * SLOTS + i];
      float as0 = 0.f, as1 = 0.f, as2 = 0.f;
      const float* xr = xf + (size_t)s * 24;
#pragma unroll
      for (int j = 0; j < 24; ++j) {
        float v = xr[j];
        as0 += v * s_v[j];
        as1 += v * s_v[24 + j];
        as2 += v * s_v[48 + j];
      }
      float w0 = __expf(lrelu(as0 + ad0)) * inv0;
      float w1 = __expf(lrelu(as1 + ad1)) * inv1;
      float w2 = __expf(lrelu(as2 + ad2)) * inv2;
      float xv = (c < 24) ? xf[(size_t)s * 24 + c] : 0.f;
      acc0 += w0 * xv; acc1 += w1 * xv; acc2 += w2 * xv;
    }
  }
  acc0 += __shfl_xor(acc0, 32, 64);
  acc1 += __shfl_xor(acc1, 32, 64);
  acc2 += __shfl_xor(acc2, 32, 64);
  if (lane < 24) {
    unsigned short* yr = Yb + (size_t)n * 72;
    yr[lane] = f2bf(acc0);
    yr[24 + lane] = f2bf(acc1);
    yr[48 + lane] = f2bf(acc2);
  }
}

// ---------------- K_gmr: fused gi-GEMM (MFMA) + GRU recurrence -------------
// Block = 16 nodes, 512 thr (8 waves). Phase 1: MFMA t-tasks striped over
// the 8 waves (tt = wv, wv+8). Phase 2: 2 serial nodes per wave (round-14's
// 4-serial at 4 waves was the 54 us bottleneck: 2500 waves for 10000 GRUs).
__global__ __launch_bounds__(512, 4) void k_gmr(
    const unsigned short* __restrict__ Yb,
    const unsigned short* __restrict__ WWt, const float* __restrict__ biasb,
    const float* __restrict__ whh, const float* __restrict__ bhh,
    const float* __restrict__ p1w, const float* __restrict__ p1b,
    const float* __restrict__ p2w, const float* __restrict__ p2b,
    float* __restrict__ out, int N) {
  __shared__ short A_lds[16][104];            // Y rows, K padded to 96
  __shared__ unsigned short gi_lds[12][16][96];
  __shared__ float s_bias[12][96];
  __shared__ float h_buf[8][36];
  __shared__ float s_o[16][12];
  int tid = threadIdx.x;
  int m0 = blockIdx.x * 16;

  // stage A: 16 rows x 36 uints (72 bf16) + zero pad k 72..103
  const unsigned int* Yu = (const unsigned int*)Yb;
  for (int u = tid; u < 16 * 36; u += 512) {
    int r = u / 36, c2 = u % 36;
    int rc = min(m0 + r, N - 1);
    *(unsigned int*)&A_lds[r][c2 * 2] = Yu[(size_t)rc * 36 + c2];
  }
  if (tid < 256) {
    int r = tid >> 4, c2 = tid & 15;
    *(unsigned int*)&A_lds[r][72 + c2 * 2] = 0;
  }
  for (int u = tid; u < 12 * 96; u += 512) s_bias[u / 96][u % 96] = biasb[u];
  __syncthreads();

  int l = tid & 63, wv = tid >> 6;  // wv 0..7
  // ---- phase 1: MFMA gi; 12 t-tasks over 8 waves ----
  {
    int mrow = l & 15;
    int koff = (l >> 4) * 8;
    bf16x8 a0 = *(const bf16x8*)&A_lds[mrow][koff];
    bf16x8 a1 = *(const bf16x8*)&A_lds[mrow][32 + koff];
    bf16x8 a2 = *(const bf16x8*)&A_lds[mrow][64 + koff];
    int rrow = (l >> 4) * 4;
    for (int tt = wv; tt < 12; tt += 8) {
#pragma unroll
      for (int nt = 0; nt < 6; ++nt) {
        int col = nt * 16 + (l & 15);
        const unsigned short* bp = WWt + ((size_t)tt * 96 + col) * 96 + koff;
        bf16x8 b0 = *(const bf16x8*)&bp[0];
        bf16x8 b1 = *(const bf16x8*)&bp[32];
        bf16x8 b2 = *(const bf16x8*)&bp[64];
        f32x4 acc = {0.f, 0.f, 0.f, 0.f};
        acc = __builtin_amdgcn_mfma_f32_16x16x32_bf16(a0, b0, acc, 0, 0, 0);
        acc = __builtin_amdgcn_mfma_f32_16x16x32_bf16(a1, b1, acc, 0, 0, 0);
        acc = __builtin_amdgcn_mfma_f32_16x16x32_bf16(a2, b2, acc, 0, 0, 0);
        float bs = s_bias[tt][col];
#pragma unroll
        for (int rg = 0; rg < 4; ++rg)
          gi_lds[tt][rrow + rg][col] = f2bf(acc[rg] + bs);
      }
    }
  }
  __syncthreads();

  // ---- phase 2: GRU recurrence, 2 serial nodes per wave ----
  int k = l & 31, jh = l >> 5;
  const float4* pr = (const float4*)(whh + (size_t)k * HID + jh * 16);
  const float4* pz = (const float4*)(whh + (size_t)(HID + k) * HID + jh * 16);
  const float4* pn = (const float4*)(whh + (size_t)(2 * HID + k) * HID + jh * 16);
  float4 wr0 = pr[0], wr1 = pr[1], wr2 = pr[2], wr3 = pr[3];
  float4 wz0 = pz[0], wz1 = pz[1], wz2 = pz[2], wz3 = pz[3];
  float4 wn0 = pn[0], wn1 = pn[1], wn2 = pn[2], wn3 = pn[3];
  float bhr = bhh[k], bhz = bhh[HID + k], bhn = bhh[2 * HID + k];
  float p1k = p1w[k];
  float p1b0 = p1b[0];

  for (int i = 0; i < 2; ++i) {
    int nl = wv * 2 + i;  // 0..15
    int node = m0 + nl;
    if (node >= N) break;  // wave-uniform
    if (jh == 0) h_buf[wv][k] = 0.f;
    float h = 0.f;
    float gr = bf2f(gi_lds[0][nl][k]);
    float gz = bf2f(gi_lds[0][nl][32 + k]);
    float gn = bf2f(gi_lds[0][nl][64 + k]);
    for (int t = 0; t < TSTEPS; ++t) {
      float gr1 = 0.f, gz1 = 0.f, gn1 = 0.f;
      if (t + 1 < TSTEPS) {
        gr1 = bf2f(gi_lds[t + 1][nl][k]);
        gz1 = bf2f(gi_lds[t + 1][nl][32 + k]);
        gn1 = bf2f(gi_lds[t + 1][nl][64 + k]);
      }
      const float* hh = &h_buf[wv][jh * 16];
      float4 h0 = *(const float4*)(hh);
      float4 h1 = *(const float4*)(hh + 4);
      float4 h2 = *(const float4*)(hh + 8);
      float4 h3 = *(const float4*)(hh + 12);
      float ar = wr0.x * h0.x + wr0.y * h0.y + wr0.z * h0.z + wr0.w * h0.w +
                 wr1.x * h1.x + wr1.y * h1.y + wr1.z * h1.z + wr1.w * h1.w +
                 wr2.x * h2.x + wr2.y * h2.y + wr2.z * h2.z + wr2.w * h2.w +
                 wr3.x * h3.x + wr3.y * h3.y + wr3.z * h3.z + wr3.w * h3.w;
      float az = wz0.x * h0.x + wz0.y * h0.y + wz0.z * h0.z + wz0.w * h0.w +
                 wz1.x * h1.x + wz1.y * h1.y + wz1.z * h1.z + wz1.w * h1.w +
                 wz2.x * h2.x + wz2.y * h2.y + wz2.z * h2.z + wz2.w * h2.w +
                 wz3.x * h3.x + wz3.y * h3.y + wz3.z * h3.z + wz3.w * h3.w;
      float an = wn0.x * h0.x + wn0.y * h0.y + wn0.z * h0.z + wn0.w * h0.w +
                 wn1.x * h1.x + wn1.y * h1.y + wn1.z * h1.z + wn1.w * h1.w +
                 wn2.x * h2.x + wn2.y * h2.y + wn2.z * h2.z + wn2.w * h2.w +
                 wn3.x * h3.x + wn3.y * h3.y + wn3.z * h3.z + wn3.w * h3.w;
      ar += __shfl_xor(ar, 32, 64);
      az += __shfl_xor(az, 32, 64);
      an += __shfl_xor(an, 32, 64);
      float r = sigm(gr + ar + bhr);
      float z = sigm(gz + az + bhz);
      float nn = tanh_fast(gn + r * (an + bhn));
      h = (1.f - z) * nn + z * h;
      if (jh == 0) h_buf[wv][k] = h;
      // on-the-fly p1 projection: o_t = sum_k p1w[k]*h_t[k] + p1b
      float po = p1k * h;
#pragma unroll
      for (int off = 16; off >= 1; off >>= 1) po += __shfl_xor(po, off, 64);
      if (l == 0) s_o[nl][t] = po + p1b0;
      gr = gr1; gz = gz1; gn = gn1;
    }
    if (l < TSTEPS) {
      float acc = p2b[l];
#pragma unroll
      for (int s2 = 0; s2 < TSTEPS; ++s2)
        acc += p2w[l * TSTEPS + s2] * s_o[nl][s2];
      out[(size_t)node * TSTEPS + l] = acc;
    }
  }
}

// ---------------------------------------------------------------------------
extern "C" void kernel_launch(void* const* d_in, const int* in_sizes, int n_in,
                              void* d_out, int out_size, void* d_ws,
                              size_t ws_size, hipStream_t stream) {
  const float* x = (const float*)d_in[0];
  const int* ei = (const int*)d_in[1];
  const float* lin_w = (const float*)d_in[2];
  const float* att_src = (const float*)d_in[3];
  const float* att_dst = (const float*)d_in[4];
  const float* gat_bias = (const float*)d_in[5];
  const float* w_ih = (const float*)d_in[6];
  const float* w_hh = (const float*)d_in[7];
  const float* b_ih = (const float*)d_in[8];
  const float* b_hh = (const float*)d_in[9];
  const float* p1w = (const float*)d_in[10];
  const float* p1b = (const float*)d_in[11];
  const float* p2w = (const float*)d_in[12];
  const float* p2b = (const float*)d_in[13];

  int N = in_sizes[0] / GAT_IN;  // 10000
  int E = in_sizes[1] / 2;       // 160000
  int ET = E + N;

  size_t off = 0;
  char* base = (char*)d_ws;
  auto alloc = [&](size_t bytes) {
    void* p = base + off;
    off += (bytes + 255) & ~(size_t)255;
    return p;
  };
  unsigned short* Yb = (unsigned short*)alloc((size_t)N * 72 * 2);  // bf16 Y
  unsigned short* WWt = (unsigned short*)alloc((size_t)12 * 96 * 96 * 2);
  float* biasb = (float*)alloc((size_t)12 * 96 * 4);
  float* vbuf = (float*)alloc(144 * 4);
  int* cnt = (int*)alloc((size_t)N * 4);
  int* slist = (int*)alloc((size_t)N * SLOTS * 4);
  (void)ws_size; (void)n_in; (void)out_size;

  int zero_blocks = (N + 95) / 96;  // 105
  k_const<<<948 + zero_blocks, 96, 0, stream>>>(lin_w, gat_bias, w_ih, b_ih,
                                                att_src, att_dst, WWt, biasb,
                                                vbuf, cnt, N);
  k_place<<<(ET + 255) / 256, 256, 0, stream>>>(ei, ei + E, cnt, slist, E, ET);
  k_aggx<<<(N + 3) / 4, 256, 0, stream>>>(x, vbuf, slist, cnt, Yb, N);
  k_gmr<<<(N + 15) / 16, 512, 0, stream>>>(Yb, WWt, biasb, w_hh, b_hh, p1w,
                                           p1b, p2w, p2b, (float*)d_out, N);
}

// Round 16
// 80.671 us; speedup vs baseline: 4.5603x; 1.0159x over previous
//
#include <hip/hip_runtime.h>
#include <math.h>

#define HEADS 3
#define C_OUT 384
#define GAT_IN 24
#define HID 32
#define TSTEPS 12
#define NEG_SLOPE 0.2f
#define CAPW 64        // per-wave cached edges in k_aggx
#define SLOTS 96       // fixed slist stride per dst (P(deg>=96) ~ 1e-30)

typedef __attribute__((ext_vector_type(8))) short bf16x8;
typedef __attribute__((ext_vector_type(4))) float f32x4;

__device__ __forceinline__ float sigm(float x) {
  return 1.f / (1.f + __expf(-x));
}
__device__ __forceinline__ float tanh_fast(float x) {
  return 2.f / (1.f + __expf(-2.f * x)) - 1.f;
}
__device__ __forceinline__ unsigned short f2bf(float x) {
  unsigned int u = __float_as_uint(x);
  unsigned int r = u + 0x7fffu + ((u >> 16) & 1u);
  return (unsigned short)(r >> 16);
}
__device__ __forceinline__ float bf2f(unsigned short u) {
  return __uint_as_float((unsigned int)u << 16);
}
__device__ __forceinline__ float lrelu(float x) {
  return x >= 0.f ? x : NEG_SLOPE * x;
}

// ---------------- K_const: WWt/biasb fold + prep + cnt zero ----------------
__global__ __launch_bounds__(96) void k_const(const float* __restrict__ lin_w,
                                              const float* __restrict__ gat_bias,
                                              const float* __restrict__ wih,
                                              const float* __restrict__ bih,
                                              const float* __restrict__ att_src,
                                              const float* __restrict__ att_dst,
                                              unsigned short* __restrict__ WWt,
                                              float* __restrict__ biasb,
                                              float* __restrict__ vbuf,
                                              int* __restrict__ cnt, int N) {
  int b = blockIdx.x;
  if (b < 876) {  // fold
    int t = b / 73, k = b % 73;
    int g = threadIdx.x;  // 0..95
    __shared__ float s_w[32];
    if (g < 32) {
      if (k < 72) {
        int h = k / 24, j = k % 24;
        s_w[g] = lin_w[(size_t)(h * C_OUT + t * 32 + g) * GAT_IN + j] * (1.f / 3.f);
      } else {
        s_w[g] = gat_bias[t * 32 + g];
      }
    }
    __syncthreads();
    const float* wrow = wih + (size_t)g * 32;
    float acc = 0.f;
#pragma unroll
    for (int c = 0; c < 32; ++c) acc += s_w[c] * wrow[c];
    if (k < 72) {
      WWt[((size_t)t * 96 + g) * 96 + k] = f2bf(acc);
      if (k < 24) WWt[((size_t)t * 96 + g) * 96 + 72 + k] = 0;  // zero pad
    } else {
      biasb[t * 96 + g] = acc + bih[g];
    }
  } else if (b < 948) {  // prep (single wave)
    int bb = b - 876;  // 0..71
    int h = bb / 24, j = bb % 24;
    int lane = threadIdx.x;
    if (lane >= 64) return;
    float as = 0.f, ad = 0.f;
    for (int c = lane; c < C_OUT; c += 64) {
      float wv = lin_w[(size_t)(h * C_OUT + c) * GAT_IN + j];
      as += att_src[h * C_OUT + c] * wv;
      ad += att_dst[h * C_OUT + c] * wv;
    }
#pragma unroll
    for (int off = 32; off >= 1; off >>= 1) {
      as += __shfl_xor(as, off, 64);
      ad += __shfl_xor(ad, off, 64);
    }
    if (lane == 0) {
      vbuf[h * 24 + j] = as;
      vbuf[72 + h * 24 + j] = ad;
    }
  } else {  // zero cnt
    int i = (b - 948) * 96 + threadIdx.x;
    if (i < N) cnt[i] = 0;
  }
}

// ---------------- K_place: bucket edges by dst, fixed stride ---------------
__global__ void k_place(const int* __restrict__ esrc,
                        const int* __restrict__ edst, int* __restrict__ cnt,
                        int* __restrict__ slist, int E, int ET) {
  int e = blockIdx.x * blockDim.x + threadIdx.x;
  if (e >= ET) return;
  int d, s;
  if (e < E) { d = edst[e]; s = esrc[e]; }
  else { d = e - E; s = e - E; }
  int pos = atomicAdd(&cnt[d], 1);
  if (pos < SLOTS) slist[(size_t)d * SLOTS + pos] = s;
}

// ---------------- K6: logits + softmax + xf-space aggregation --------------
__global__ __launch_bounds__(256) void k_aggx(
    const float* __restrict__ xf, const float* __restrict__ vbuf,
    const int* __restrict__ slist, const int* __restrict__ cnt,
    unsigned short* __restrict__ Yb, int N) {
  __shared__ float s_v[144];
  __shared__ float s_w[4][CAPW][3];
  __shared__ unsigned short s_xb[4][CAPW][26];  // bf16 xf rows
  int tid = threadIdx.x, lane = tid & 63, wv = tid >> 6;
  if (tid < 144) s_v[tid] = vbuf[tid];
  __syncthreads();  // before any wave can exit
  int n = blockIdx.x * 4 + wv;
  if (n >= N) return;  // per-wave exit; no barriers below

  int deg = min(cnt[n], SLOTS);

  float xl = (lane < 24) ? xf[(size_t)n * 24 + lane] : 0.f;
  float ad0, ad1, ad2;
  {
    float p0 = (lane < 24) ? xl * s_v[72 + lane] : 0.f;
    float p1 = (lane < 24) ? xl * s_v[96 + lane] : 0.f;
    float p2 = (lane < 24) ? xl * s_v[120 + lane] : 0.f;
#pragma unroll
    for (int off = 32; off >= 1; off >>= 1) {
      p0 += __shfl_xor(p0, off, 64);
      p1 += __shfl_xor(p1, off, 64);
      p2 += __shfl_xor(p2, off, 64);
    }
    ad0 = p0; ad1 = p1; ad2 = p2;
  }

  float t0 = 0.f, t1 = 0.f, t2 = 0.f;
  for (int i = lane; i < deg; i += 64) {
    int s = slist[(size_t)n * SLOTS + i];
    const float4* xr = (const float4*)(xf + (size_t)s * 24);
    float xs[24];
#pragma unroll
    for (int q = 0; q < 6; ++q) {
      float4 v = xr[q];
      xs[4 * q] = v.x; xs[4 * q + 1] = v.y;
      xs[4 * q + 2] = v.z; xs[4 * q + 3] = v.w;
    }
    float as0 = 0.f, as1 = 0.f, as2 = 0.f;
#pragma unroll
    for (int j = 0; j < 24; ++j) {
      float v = xs[j];
      as0 += v * s_v[j];
      as1 += v * s_v[24 + j];
      as2 += v * s_v[48 + j];
    }
    float e0 = __expf(lrelu(as0 + ad0));
    float e1 = __expf(lrelu(as1 + ad1));
    float e2 = __expf(lrelu(as2 + ad2));
    if (i < CAPW) {
      s_w[wv][i][0] = e0; s_w[wv][i][1] = e1; s_w[wv][i][2] = e2;
#pragma unroll
      for (int j = 0; j < 24; ++j) s_xb[wv][i][j] = f2bf(xs[j]);
    }
    t0 += e0; t1 += e1; t2 += e2;
  }
#pragma unroll
  for (int off = 32; off >= 1; off >>= 1) {
    t0 += __shfl_xor(t0, off, 64);
    t1 += __shfl_xor(t1, off, 64);
    t2 += __shfl_xor(t2, off, 64);
  }
  float inv0 = 1.f / t0, inv1 = 1.f / t1, inv2 = 1.f / t2;

  int eg = lane >> 5;   // edge slot 0/1
  int c = lane & 31;    // channel (active c<24)
  float acc0 = 0.f, acc1 = 0.f, acc2 = 0.f;
  if (deg <= CAPW) {
    int cc = (c < 24) ? c : 0;
    float cmask = (c < 24) ? 1.f : 0.f;
#pragma unroll 2
    for (int i = eg; i < deg; i += 2) {
      float w0 = s_w[wv][i][0] * inv0;
      float w1 = s_w[wv][i][1] * inv1;
      float w2 = s_w[wv][i][2] * inv2;
      float xv = bf2f(s_xb[wv][i][cc]) * cmask;
      acc0 += w0 * xv; acc1 += w1 * xv; acc2 += w2 * xv;
    }
  } else {
    for (int i = eg; i < deg; i += 2) {
      int s = slist[(size_t)n * SLOTS + i];
      float as0 = 0.f, as1 = 0.f, as2 = 0.f;
      const float* xr = xf + (size_t)s * 24;
#pragma unroll
      for (int j = 0; j < 24; ++j) {
        float v = xr[j];
        as0 += v * s_v[j];
        as1 += v * s_v[24 + j];
        as2 += v * s_v[48 + j];
      }
      float w0 = __expf(lrelu(as0 + ad0)) * inv0;
      float w1 = __expf(lrelu(as1 + ad1)) * inv1;
      float w2 = __expf(lrelu(as2 + ad2)) * inv2;
      float xv = (c < 24) ? xf[(size_t)s * 24 + c] : 0.f;
      acc0 += w0 * xv; acc1 += w1 * xv; acc2 += w2 * xv;
    }
  }
  acc0 += __shfl_xor(acc0, 32, 64);
  acc1 += __shfl_xor(acc1, 32, 64);
  acc2 += __shfl_xor(acc2, 32, 64);
  if (lane < 24) {
    unsigned short* yr = Yb + (size_t)n * 72;
    yr[lane] = f2bf(acc0);
    yr[24 + lane] = f2bf(acc1);
    yr[48 + lane] = f2bf(acc2);
  }
}

// ---------------- K_gmr: fused gi-GEMM (MFMA) + GRU recurrence -------------
// Block = 16 nodes, 512 thr (8 waves). Phase 1: MFMA t-tasks striped over
// 8 waves. Phase 2: each wave runs its 2 nodes INTERLEAVED in one t-loop
// (dual dependency chains hide each other's latency; weights shared).
// launch_bounds(512,2): VGPR cap 256 so the 12 float4 weights stay resident
// (round-15's (512,4) clamped to 48 VGPR -> per-step weight reload).
__global__ __launch_bounds__(512, 2) void k_gmr(
    const unsigned short* __restrict__ Yb,
    const unsigned short* __restrict__ WWt, const float* __restrict__ biasb,
    const float* __restrict__ whh, const float* __restrict__ bhh,
    const float* __restrict__ p1w, const float* __restrict__ p1b,
    const float* __restrict__ p2w, const float* __restrict__ p2b,
    float* __restrict__ out, int N) {
  __shared__ short A_lds[16][104];            // Y rows, K padded to 96
  __shared__ unsigned short gi_lds[12][16][96];
  __shared__ float s_bias[12][96];
  __shared__ float h_buf[8][72];              // [wv][0..35]=A, [36..71]=B
  __shared__ float s_o[16][12];
  int tid = threadIdx.x;
  int m0 = blockIdx.x * 16;

  // stage A: 16 rows x 36 uints (72 bf16) + zero pad k 72..103
  const unsigned int* Yu = (const unsigned int*)Yb;
  for (int u = tid; u < 16 * 36; u += 512) {
    int r = u / 36, c2 = u % 36;
    int rc = min(m0 + r, N - 1);
    *(unsigned int*)&A_lds[r][c2 * 2] = Yu[(size_t)rc * 36 + c2];
  }
  if (tid < 256) {
    int r = tid >> 4, c2 = tid & 15;
    *(unsigned int*)&A_lds[r][72 + c2 * 2] = 0;
  }
  for (int u = tid; u < 12 * 96; u += 512) s_bias[u / 96][u % 96] = biasb[u];
  __syncthreads();

  int l = tid & 63, wv = tid >> 6;  // wv 0..7
  // ---- phase 1: MFMA gi; 12 t-tasks over 8 waves ----
  {
    int mrow = l & 15;
    int koff = (l >> 4) * 8;
    bf16x8 a0 = *(const bf16x8*)&A_lds[mrow][koff];
    bf16x8 a1 = *(const bf16x8*)&A_lds[mrow][32 + koff];
    bf16x8 a2 = *(const bf16x8*)&A_lds[mrow][64 + koff];
    int rrow = (l >> 4) * 4;
    for (int tt = wv; tt < 12; tt += 8) {
#pragma unroll
      for (int nt = 0; nt < 6; ++nt) {
        int col = nt * 16 + (l & 15);
        const unsigned short* bp = WWt + ((size_t)tt * 96 + col) * 96 + koff;
        bf16x8 b0 = *(const bf16x8*)&bp[0];
        bf16x8 b1 = *(const bf16x8*)&bp[32];
        bf16x8 b2 = *(const bf16x8*)&bp[64];
        f32x4 acc = {0.f, 0.f, 0.f, 0.f};
        acc = __builtin_amdgcn_mfma_f32_16x16x32_bf16(a0, b0, acc, 0, 0, 0);
        acc = __builtin_amdgcn_mfma_f32_16x16x32_bf16(a1, b1, acc, 0, 0, 0);
        acc = __builtin_amdgcn_mfma_f32_16x16x32_bf16(a2, b2, acc, 0, 0, 0);
        float bs = s_bias[tt][col];
#pragma unroll
        for (int rg = 0; rg < 4; ++rg)
          gi_lds[tt][rrow + rg][col] = f2bf(acc[rg] + bs);
      }
    }
  }
  __syncthreads();

  // ---- phase 2: dual-node interleaved GRU recurrence ----
  int k = l & 31, jh = l >> 5;
  const float4* pr = (const float4*)(whh + (size_t)k * HID + jh * 16);
  const float4* pz = (const float4*)(whh + (size_t)(HID + k) * HID + jh * 16);
  const float4* pn = (const float4*)(whh + (size_t)(2 * HID + k) * HID + jh * 16);
  float4 wr0 = pr[0], wr1 = pr[1], wr2 = pr[2], wr3 = pr[3];
  float4 wz0 = pz[0], wz1 = pz[1], wz2 = pz[2], wz3 = pz[3];
  float4 wn0 = pn[0], wn1 = pn[1], wn2 = pn[2], wn3 = pn[3];
  float bhr = bhh[k], bhz = bhh[HID + k], bhn = bhh[2 * HID + k];
  float p1k = p1w[k];
  float p1b0 = p1b[0];

  int nlA = wv * 2, nlB = nlA + 1;
  int nodeA = m0 + nlA, nodeB = m0 + nlB;
  if (nodeA < N) {  // wave-uniform; no barriers inside
    bool hasB = (nodeB < N);
    int nlBc = hasB ? nlB : nlA;
    if (jh == 0) { h_buf[wv][k] = 0.f; h_buf[wv][36 + k] = 0.f; }
    float hA = 0.f, hB = 0.f;
    float grA = bf2f(gi_lds[0][nlA][k]);
    float gzA = bf2f(gi_lds[0][nlA][32 + k]);
    float gnA = bf2f(gi_lds[0][nlA][64 + k]);
    float grB = bf2f(gi_lds[0][nlBc][k]);
    float gzB = bf2f(gi_lds[0][nlBc][32 + k]);
    float gnB = bf2f(gi_lds[0][nlBc][64 + k]);
    for (int t = 0; t < TSTEPS; ++t) {
      float grA1 = 0.f, gzA1 = 0.f, gnA1 = 0.f;
      float grB1 = 0.f, gzB1 = 0.f, gnB1 = 0.f;
      if (t + 1 < TSTEPS) {
        grA1 = bf2f(gi_lds[t + 1][nlA][k]);
        gzA1 = bf2f(gi_lds[t + 1][nlA][32 + k]);
        gnA1 = bf2f(gi_lds[t + 1][nlA][64 + k]);
        grB1 = bf2f(gi_lds[t + 1][nlBc][k]);
        gzB1 = bf2f(gi_lds[t + 1][nlBc][32 + k]);
        gnB1 = bf2f(gi_lds[t + 1][nlBc][64 + k]);
      }
      const float* hhA = &h_buf[wv][jh * 16];
      const float* hhB = &h_buf[wv][36 + jh * 16];
      float4 a0 = *(const float4*)(hhA);
      float4 a1 = *(const float4*)(hhA + 4);
      float4 a2 = *(const float4*)(hhA + 8);
      float4 a3 = *(const float4*)(hhA + 12);
      float4 b0 = *(const float4*)(hhB);
      float4 b1 = *(const float4*)(hhB + 4);
      float4 b2 = *(const float4*)(hhB + 8);
      float4 b3 = *(const float4*)(hhB + 12);
      float arA = wr0.x * a0.x + wr0.y * a0.y + wr0.z * a0.z + wr0.w * a0.w +
                  wr1.x * a1.x + wr1.y * a1.y + wr1.z * a1.z + wr1.w * a1.w +
                  wr2.x * a2.x + wr2.y * a2.y + wr2.z * a2.z + wr2.w * a2.w +
                  wr3.x * a3.x + wr3.y * a3.y + wr3.z * a3.z + wr3.w * a3.w;
      float arB = wr0.x * b0.x + wr0.y * b0.y + wr0.z * b0.z + wr0.w * b0.w +
                  wr1.x * b1.x + wr1.y * b1.y + wr1.z * b1.z + wr1.w * b1.w +
                  wr2.x * b2.x + wr2.y * b2.y + wr2.z * b2.z + wr2.w * b2.w +
                  wr3.x * b3.x + wr3.y * b3.y + wr3.z * b3.z + wr3.w * b3.w;
      float azA = wz0.x * a0.x + wz0.y * a0.y + wz0.z * a0.z + wz0.w * a0.w +
                  wz1.x * a1.x + wz1.y * a1.y + wz1.z * a1.z + wz1.w * a1.w +
                  wz2.x * a2.x + wz2.y * a2.y + wz2.z * a2.z + wz2.w * a2.w +
                  wz3.x * a3.x + wz3.y * a3.y + wz3.z * a3.z + wz3.w * a3.w;
      float azB = wz0.x * b0.x + wz0.y * b0.y + wz0.z * b0.z + wz0.w * b0.w +
                  wz1.x * b1.x + wz1.y * b1.y + wz1.z * b1.z + wz1.w * b1.w +
                  wz2.x * b2.x + wz2.y * b2.y + wz2.z * b2.z + wz2.w * b2.w +
                  wz3.x * b3.x + wz3.y * b3.y + wz3.z * b3.z + wz3.w * b3.w;
      float anA = wn0.x * a0.x + wn0.y * a0.y + wn0.z * a0.z + wn0.w * a0.w +
                  wn1.x * a1.x + wn1.y * a1.y + wn1.z * a1.z + wn1.w * a1.w +
                  wn2.x * a2.x + wn2.y * a2.y + wn2.z * a2.z + wn2.w * a2.w +
                  wn3.x * a3.x + wn3.y * a3.y + wn3.z * a3.z + wn3.w * a3.w;
      float anB = wn0.x * b0.x + wn0.y * b0.y + wn0.z * b0.z + wn0.w * b0.w +
                  wn1.x * b1.x + wn1.y * b1.y + wn1.z * b1.z + wn1.w * b1.w +
                  wn2.x * b2.x + wn2.y * b2.y + wn2.z * b2.z + wn2.w * b2.w +
                  wn3.x * b3.x + wn3.y * b3.y + wn3.z * b3.z + wn3.w * b3.w;
      arA += __shfl_xor(arA, 32, 64);
      arB += __shfl_xor(arB, 32, 64);
      azA += __shfl_xor(azA, 32, 64);
      azB += __shfl_xor(azB, 32, 64);
      anA += __shfl_xor(anA, 32, 64);
      anB += __shfl_xor(anB, 32, 64);
      float rA = sigm(grA + arA + bhr);
      float rB = sigm(grB + arB + bhr);
      float zA = sigm(gzA + azA + bhz);
      float zB = sigm(gzB + azB + bhz);
      float nnA = tanh_fast(gnA + rA * (anA + bhn));
      float nnB = tanh_fast(gnB + rB * (anB + bhn));
      hA = (1.f - zA) * nnA + zA * hA;
      hB = (1.f - zB) * nnB + zB * hB;
      if (jh == 0) { h_buf[wv][k] = hA; h_buf[wv][36 + k] = hB; }
      float poA = p1k * hA;
      float poB = p1k * hB;
#pragma unroll
      for (int off = 16; off >= 1; off >>= 1) {
        poA += __shfl_xor(poA, off, 64);
        poB += __shfl_xor(poB, off, 64);
      }
      if (l == 0) {
        s_o[nlA][t] = poA + p1b0;
        if (hasB) s_o[nlB][t] = poB + p1b0;
      }
      grA = grA1; gzA = gzA1; gnA = gnA1;
      grB = grB1; gzB = gzB1; gnB = gnB1;
    }
    if (l < TSTEPS) {
      float accA = p2b[l], accB = accA;
#pragma unroll
      for (int s2 = 0; s2 < TSTEPS; ++s2) {
        float w = p2w[l * TSTEPS + s2];
        accA += w * s_o[nlA][s2];
        accB += w * s_o[nlBc][s2];
      }
      out[(size_t)nodeA * TSTEPS + l] = accA;
      if (hasB) out[(size_t)nodeB * TSTEPS + l] = accB;
    }
  }
}

// ---------------------------------------------------------------------------
extern "C" void kernel_launch(void* const* d_in, const int* in_sizes, int n_in,
                              void* d_out, int out_size, void* d_ws,
                              size_t ws_size, hipStream_t stream) {
  const float* x = (const float*)d_in[0];
  const int* ei = (const int*)d_in[1];
  const float* lin_w = (const float*)d_in[2];
  const float* att_src = (const float*)d_in[3];
  const float* att_dst = (const float*)d_in[4];
  const float* gat_bias = (const float*)d_in[5];
  const float* w_ih = (const float*)d_in[6];
  const float* w_hh = (const float*)d_in[7];
  const float* b_ih = (const float*)d_in[8];
  const float* b_hh = (const float*)d_in[9];
  const float* p1w = (const float*)d_in[10];
  const float* p1b = (const float*)d_in[11];
  const float* p2w = (const float*)d_in[12];
  const float* p2b = (const float*)d_in[13];

  int N = in_sizes[0] / GAT_IN;  // 10000
  int E = in_sizes[1] / 2;       // 160000
  int ET = E + N;

  size_t off = 0;
  char* base = (char*)d_ws;
  auto alloc = [&](size_t bytes) {
    void* p = base + off;
    off += (bytes + 255) & ~(size_t)255;
    return p;
  };
  unsigned short* Yb = (unsigned short*)alloc((size_t)N * 72 * 2);  // bf16 Y
  unsigned short* WWt = (unsigned short*)alloc((size_t)12 * 96 * 96 * 2);
  float* biasb = (float*)alloc((size_t)12 * 96 * 4);
  float* vbuf = (float*)alloc(144 * 4);
  int* cnt = (int*)alloc((size_t)N * 4);
  int* slist = (int*)alloc((size_t)N * SLOTS * 4);
  (void)ws_size; (void)n_in; (void)out_size;

  int zero_blocks = (N + 95) / 96;  // 105
  k_const<<<948 + zero_blocks, 96, 0, stream>>>(lin_w, gat_bias, w_ih, b_ih,
                                                att_src, att_dst, WWt, biasb,
                                                vbuf, cnt, N);
  k_place<<<(ET + 255) / 256, 256, 0, stream>>>(ei, ei + E, cnt, slist, E, ET);
  k_aggx<<<(N + 3) / 4, 256, 0, stream>>>(x, vbuf, slist, cnt, Yb, N);
  k_gmr<<<(N + 15) / 16, 512, 0, stream>>>(Yb, WWt, biasb, w_hh, b_hh, p1w,
                                           p1b, p2w, p2b, (float*)d_out, N);
}

// Round 17
// 80.336 us; speedup vs baseline: 4.5793x; 1.0042x over previous
//
#include <hip/hip_runtime.h>
#include <math.h>

#define HEADS 3
#define C_OUT 384
#define GAT_IN 24
#define HID 32
#define TSTEPS 12
#define NEG_SLOPE 0.2f
#define CAPW 64        // per-wave cached edges in k_aggx
#define SLOTS 96       // fixed slist stride per dst (P(deg>=96) ~ 1e-30)

typedef __attribute__((ext_vector_type(8))) short bf16x8;
typedef __attribute__((ext_vector_type(4))) float f32x4;

__device__ __forceinline__ float sigm(float x) {
  return 1.f / (1.f + __expf(-x));
}
__device__ __forceinline__ float tanh_fast(float x) {
  return 2.f / (1.f + __expf(-2.f * x)) - 1.f;
}
__device__ __forceinline__ unsigned short f2bf(float x) {
  unsigned int u = __float_as_uint(x);
  unsigned int r = u + 0x7fffu + ((u >> 16) & 1u);
  return (unsigned short)(r >> 16);
}
__device__ __forceinline__ float bf2f(unsigned short u) {
  return __uint_as_float((unsigned int)u << 16);
}
__device__ __forceinline__ float lrelu(float x) {
  return x >= 0.f ? x : NEG_SLOPE * x;
}

// ---------------- K_const: WWt/biasb fold + prep + cnt zero ----------------
__global__ __launch_bounds__(96) void k_const(const float* __restrict__ lin_w,
                                              const float* __restrict__ gat_bias,
                                              const float* __restrict__ wih,
                                              const float* __restrict__ bih,
                                              const float* __restrict__ att_src,
                                              const float* __restrict__ att_dst,
                                              unsigned short* __restrict__ WWt,
                                              float* __restrict__ biasb,
                                              float* __restrict__ vbuf,
                                              int* __restrict__ cnt, int N) {
  int b = blockIdx.x;
  if (b < 876) {  // fold
    int t = b / 73, k = b % 73;
    int g = threadIdx.x;  // 0..95
    __shared__ float s_w[32];
    if (g < 32) {
      if (k < 72) {
        int h = k / 24, j = k % 24;
        s_w[g] = lin_w[(size_t)(h * C_OUT + t * 32 + g) * GAT_IN + j] * (1.f / 3.f);
      } else {
        s_w[g] = gat_bias[t * 32 + g];
      }
    }
    __syncthreads();
    const float* wrow = wih + (size_t)g * 32;
    float acc = 0.f;
#pragma unroll
    for (int c = 0; c < 32; ++c) acc += s_w[c] * wrow[c];
    if (k < 72) {
      WWt[((size_t)t * 96 + g) * 96 + k] = f2bf(acc);
      if (k < 24) WWt[((size_t)t * 96 + g) * 96 + 72 + k] = 0;  // zero pad
    } else {
      biasb[t * 96 + g] = acc + bih[g];
    }
  } else if (b < 948) {  // prep (single wave)
    int bb = b - 876;  // 0..71
    int h = bb / 24, j = bb % 24;
    int lane = threadIdx.x;
    if (lane >= 64) return;
    float as = 0.f, ad = 0.f;
    for (int c = lane; c < C_OUT; c += 64) {
      float wv = lin_w[(size_t)(h * C_OUT + c) * GAT_IN + j];
      as += att_src[h * C_OUT + c] * wv;
      ad += att_dst[h * C_OUT + c] * wv;
    }
#pragma unroll
    for (int off = 32; off >= 1; off >>= 1) {
      as += __shfl_xor(as, off, 64);
      ad += __shfl_xor(ad, off, 64);
    }
    if (lane == 0) {
      vbuf[h * 24 + j] = as;
      vbuf[72 + h * 24 + j] = ad;
    }
  } else {  // zero cnt
    int i = (b - 948) * 96 + threadIdx.x;
    if (i < N) cnt[i] = 0;
  }
}

// ---------------- K_place: bucket edges by dst, fixed stride ---------------
__global__ void k_place(const int* __restrict__ esrc,
                        const int* __restrict__ edst, int* __restrict__ cnt,
                        int* __restrict__ slist, int E, int ET) {
  int e = blockIdx.x * blockDim.x + threadIdx.x;
  if (e >= ET) return;
  int d, s;
  if (e < E) { d = edst[e]; s = esrc[e]; }
  else { d = e - E; s = e - E; }
  int pos = atomicAdd(&cnt[d], 1);
  if (pos < SLOTS) slist[(size_t)d * SLOTS + pos] = s;
}

// ---------------- K6: logits + softmax + xf-space aggregation --------------
__global__ __launch_bounds__(256) void k_aggx(
    const float* __restrict__ xf, const float* __restrict__ vbuf,
    const int* __restrict__ slist, const int* __restrict__ cnt,
    unsigned short* __restrict__ Yb, int N) {
  __shared__ float s_v[144];
  __shared__ float s_w[4][CAPW][3];
  __shared__ unsigned short s_xb[4][CAPW][26];  // bf16 xf rows
  int tid = threadIdx.x, lane = tid & 63, wv = tid >> 6;
  if (tid < 144) s_v[tid] = vbuf[tid];
  __syncthreads();  // before any wave can exit
  int n = blockIdx.x * 4 + wv;
  if (n >= N) return;  // per-wave exit; no barriers below

  int deg = min(cnt[n], SLOTS);

  float xl = (lane < 24) ? xf[(size_t)n * 24 + lane] : 0.f;
  float ad0, ad1, ad2;
  {
    float p0 = (lane < 24) ? xl * s_v[72 + lane] : 0.f;
    float p1 = (lane < 24) ? xl * s_v[96 + lane] : 0.f;
    float p2 = (lane < 24) ? xl * s_v[120 + lane] : 0.f;
#pragma unroll
    for (int off = 32; off >= 1; off >>= 1) {
      p0 += __shfl_xor(p0, off, 64);
      p1 += __shfl_xor(p1, off, 64);
      p2 += __shfl_xor(p2, off, 64);
    }
    ad0 = p0; ad1 = p1; ad2 = p2;
  }

  float t0 = 0.f, t1 = 0.f, t2 = 0.f;
  for (int i = lane; i < deg; i += 64) {
    int s = slist[(size_t)n * SLOTS + i];
    const float4* xr = (const float4*)(xf + (size_t)s * 24);
    float xs[24];
#pragma unroll
    for (int q = 0; q < 6; ++q) {
      float4 v = xr[q];
      xs[4 * q] = v.x; xs[4 * q + 1] = v.y;
      xs[4 * q + 2] = v.z; xs[4 * q + 3] = v.w;
    }
    float as0 = 0.f, as1 = 0.f, as2 = 0.f;
#pragma unroll
    for (int j = 0; j < 24; ++j) {
      float v = xs[j];
      as0 += v * s_v[j];
      as1 += v * s_v[24 + j];
      as2 += v * s_v[48 + j];
    }
    float e0 = __expf(lrelu(as0 + ad0));
    float e1 = __expf(lrelu(as1 + ad1));
    float e2 = __expf(lrelu(as2 + ad2));
    if (i < CAPW) {
      s_w[wv][i][0] = e0; s_w[wv][i][1] = e1; s_w[wv][i][2] = e2;
#pragma unroll
      for (int j = 0; j < 24; ++j) s_xb[wv][i][j] = f2bf(xs[j]);
    }
    t0 += e0; t1 += e1; t2 += e2;
  }
#pragma unroll
  for (int off = 32; off >= 1; off >>= 1) {
    t0 += __shfl_xor(t0, off, 64);
    t1 += __shfl_xor(t1, off, 64);
    t2 += __shfl_xor(t2, off, 64);
  }
  float inv0 = 1.f / t0, inv1 = 1.f / t1, inv2 = 1.f / t2;

  int eg = lane >> 5;   // edge slot 0/1
  int c = lane & 31;    // channel (active c<24)
  float acc0 = 0.f, acc1 = 0.f, acc2 = 0.f;
  if (deg <= CAPW) {
    int cc = (c < 24) ? c : 0;
    float cmask = (c < 24) ? 1.f : 0.f;
#pragma unroll 2
    for (int i = eg; i < deg; i += 2) {
      float w0 = s_w[wv][i][0] * inv0;
      float w1 = s_w[wv][i][1] * inv1;
      float w2 = s_w[wv][i][2] * inv2;
      float xv = bf2f(s_xb[wv][i][cc]) * cmask;
      acc0 += w0 * xv; acc1 += w1 * xv; acc2 += w2 * xv;
    }
  } else {
    for (int i = eg; i < deg; i += 2) {
      int s = slist[(size_t)n * SLOTS + i];
      float as0 = 0.f, as1 = 0.f, as2 = 0.f;
      const float* xr = xf + (size_t)s * 24;
#pragma unroll
      for (int j = 0; j < 24; ++j) {
        float v = xr[j];
        as0 += v * s_v[j];
        as1 += v * s_v[24 + j];
        as2 += v * s_v[48 + j];
      }
      float w0 = __expf(lrelu(as0 + ad0)) * inv0;
      float w1 = __expf(lrelu(as1 + ad1)) * inv1;
      float w2 = __expf(lrelu(as2 + ad2)) * inv2;
      float xv = (c < 24) ? xf[(size_t)s * 24 + c] : 0.f;
      acc0 += w0 * xv; acc1 += w1 * xv; acc2 += w2 * xv;
    }
  }
  acc0 += __shfl_xor(acc0, 32, 64);
  acc1 += __shfl_xor(acc1, 32, 64);
  acc2 += __shfl_xor(acc2, 32, 64);
  if (lane < 24) {
    unsigned short* yr = Yb + (size_t)n * 72;
    yr[lane] = f2bf(acc0);
    yr[24 + lane] = f2bf(acc1);
    yr[48 + lane] = f2bf(acc2);
  }
}

// ---------------- K_gmr: fused gi-GEMM (MFMA) + GRU recurrence -------------
// Block = 16 nodes, 512 thr (8 waves). Phase 1: MFMA t-tasks striped over
// 8 waves. Phase 2: 2 nodes interleaved per wave. w_hh staged in LDS, and
// each lane's 12 float4 weights are loaded FROM LDS into registers: the
// in-loop LDS stores (h_buf/s_o) make rematerialization illegal, so the
// compiler must keep them register-resident (rounds 14-16: global weight
// loads were rematerialized every t-step at VGPR=48..84 -> 2000 cyc/step).
__global__ __launch_bounds__(512, 2) void k_gmr(
    const unsigned short* __restrict__ Yb,
    const unsigned short* __restrict__ WWt, const float* __restrict__ biasb,
    const float* __restrict__ whh, const float* __restrict__ bhh,
    const float* __restrict__ p1w, const float* __restrict__ p1b,
    const float* __restrict__ p2w, const float* __restrict__ p2b,
    float* __restrict__ out, int N) {
  __shared__ short A_lds[16][104];            // Y rows, K padded to 96
  __shared__ unsigned short gi_lds[12][16][96];
  __shared__ float s_bias[12][96];
  __shared__ float whh_lds[96][36];           // 144B rows: b128-aligned
  __shared__ float h_buf[8][72];              // [wv][0..35]=A, [36..71]=B
  __shared__ float s_o[16][12];
  int tid = threadIdx.x;
  int m0 = blockIdx.x * 16;

  // stage A: 16 rows x 36 uints (72 bf16) + zero pad k 72..103
  const unsigned int* Yu = (const unsigned int*)Yb;
  for (int u = tid; u < 16 * 36; u += 512) {
    int r = u / 36, c2 = u % 36;
    int rc = min(m0 + r, N - 1);
    *(unsigned int*)&A_lds[r][c2 * 2] = Yu[(size_t)rc * 36 + c2];
  }
  if (tid < 256) {
    int r = tid >> 4, c2 = tid & 15;
    *(unsigned int*)&A_lds[r][72 + c2 * 2] = 0;
  }
  for (int u = tid; u < 12 * 96; u += 512) s_bias[u / 96][u % 96] = biasb[u];
  for (int u = tid; u < 96 * 32; u += 512) whh_lds[u >> 5][u & 31] = whh[u];
  __syncthreads();

  int l = tid & 63, wv = tid >> 6;  // wv 0..7
  // ---- phase 1: MFMA gi; 12 t-tasks over 8 waves ----
  {
    int mrow = l & 15;
    int koff = (l >> 4) * 8;
    bf16x8 a0 = *(const bf16x8*)&A_lds[mrow][koff];
    bf16x8 a1 = *(const bf16x8*)&A_lds[mrow][32 + koff];
    bf16x8 a2 = *(const bf16x8*)&A_lds[mrow][64 + koff];
    int rrow = (l >> 4) * 4;
    for (int tt = wv; tt < 12; tt += 8) {
#pragma unroll
      for (int nt = 0; nt < 6; ++nt) {
        int col = nt * 16 + (l & 15);
        const unsigned short* bp = WWt + ((size_t)tt * 96 + col) * 96 + koff;
        bf16x8 b0 = *(const bf16x8*)&bp[0];
        bf16x8 b1 = *(const bf16x8*)&bp[32];
        bf16x8 b2 = *(const bf16x8*)&bp[64];
        f32x4 acc = {0.f, 0.f, 0.f, 0.f};
        acc = __builtin_amdgcn_mfma_f32_16x16x32_bf16(a0, b0, acc, 0, 0, 0);
        acc = __builtin_amdgcn_mfma_f32_16x16x32_bf16(a1, b1, acc, 0, 0, 0);
        acc = __builtin_amdgcn_mfma_f32_16x16x32_bf16(a2, b2, acc, 0, 0, 0);
        float bs = s_bias[tt][col];
#pragma unroll
        for (int rg = 0; rg < 4; ++rg)
          gi_lds[tt][rrow + rg][col] = f2bf(acc[rg] + bs);
      }
    }
  }
  __syncthreads();

  // ---- phase 2: dual-node interleaved GRU recurrence ----
  int k = l & 31, jh = l >> 5;
  const float* wpr = &whh_lds[k][jh * 16];
  const float* wpz = &whh_lds[32 + k][jh * 16];
  const float* wpn = &whh_lds[64 + k][jh * 16];
  float4 wr0 = *(const float4*)(wpr);
  float4 wr1 = *(const float4*)(wpr + 4);
  float4 wr2 = *(const float4*)(wpr + 8);
  float4 wr3 = *(const float4*)(wpr + 12);
  float4 wz0 = *(const float4*)(wpz);
  float4 wz1 = *(const float4*)(wpz + 4);
  float4 wz2 = *(const float4*)(wpz + 8);
  float4 wz3 = *(const float4*)(wpz + 12);
  float4 wn0 = *(const float4*)(wpn);
  float4 wn1 = *(const float4*)(wpn + 4);
  float4 wn2 = *(const float4*)(wpn + 8);
  float4 wn3 = *(const float4*)(wpn + 12);
  float bhr = bhh[k], bhz = bhh[HID + k], bhn = bhh[2 * HID + k];
  float p1k = p1w[k];
  float p1b0 = p1b[0];

  int nlA = wv * 2, nlB = nlA + 1;
  int nodeA = m0 + nlA, nodeB = m0 + nlB;
  if (nodeA < N) {  // wave-uniform; no barriers inside
    bool hasB = (nodeB < N);
    int nlBc = hasB ? nlB : nlA;
    if (jh == 0) { h_buf[wv][k] = 0.f; h_buf[wv][36 + k] = 0.f; }
    float hA = 0.f, hB = 0.f;
    for (int t = 0; t < TSTEPS; ++t) {
      float grA = bf2f(gi_lds[t][nlA][k]);
      float gzA = bf2f(gi_lds[t][nlA][32 + k]);
      float gnA = bf2f(gi_lds[t][nlA][64 + k]);
      float grB = bf2f(gi_lds[t][nlBc][k]);
      float gzB = bf2f(gi_lds[t][nlBc][32 + k]);
      float gnB = bf2f(gi_lds[t][nlBc][64 + k]);
      const float* hhA = &h_buf[wv][jh * 16];
      const float* hhB = &h_buf[wv][36 + jh * 16];
      float4 a0 = *(const float4*)(hhA);
      float4 a1 = *(const float4*)(hhA + 4);
      float4 a2 = *(const float4*)(hhA + 8);
      float4 a3 = *(const float4*)(hhA + 12);
      float4 b0 = *(const float4*)(hhB);
      float4 b1 = *(const float4*)(hhB + 4);
      float4 b2 = *(const float4*)(hhB + 8);
      float4 b3 = *(const float4*)(hhB + 12);
      float arA = wr0.x * a0.x + wr0.y * a0.y + wr0.z * a0.z + wr0.w * a0.w +
                  wr1.x * a1.x + wr1.y * a1.y + wr1.z * a1.z + wr1.w * a1.w +
                  wr2.x * a2.x + wr2.y * a2.y + wr2.z * a2.z + wr2.w * a2.w +
                  wr3.x * a3.x + wr3.y * a3.y + wr3.z * a3.z + wr3.w * a3.w;
      float arB = wr0.x * b0.x + wr0.y * b0.y + wr0.z * b0.z + wr0.w * b0.w +
                  wr1.x * b1.x + wr1.y * b1.y + wr1.z * b1.z + wr1.w * b1.w +
                  wr2.x * b2.x + wr2.y * b2.y + wr2.z * b2.z + wr2.w * b2.w +
                  wr3.x * b3.x + wr3.y * b3.y + wr3.z * b3.z + wr3.w * b3.w;
      float azA = wz0.x * a0.x + wz0.y * a0.y + wz0.z * a0.z + wz0.w * a0.w +
                  wz1.x * a1.x + wz1.y * a1.y + wz1.z * a1.z + wz1.w * a1.w +
                  wz2.x * a2.x + wz2.y * a2.y + wz2.z * a2.z + wz2.w * a2.w +
                  wz3.x * a3.x + wz3.y * a3.y + wz3.z * a3.z + wz3.w * a3.w;
      float azB = wz0.x * b0.x + wz0.y * b0.y + wz0.z * b0.z + wz0.w * b0.w +
                  wz1.x * b1.x + wz1.y * b1.y + wz1.z * b1.z + wz1.w * b1.w +
                  wz2.x * b2.x + wz2.y * b2.y + wz2.z * b2.z + wz2.w * b2.w +
                  wz3.x * b3.x + wz3.y * b3.y + wz3.z * b3.z + wz3.w * b3.w;
      float anA = wn0.x * a0.x + wn0.y * a0.y + wn0.z * a0.z + wn0.w * a0.w +
                  wn1.x * a1.x + wn1.y * a1.y + wn1.z * a1.z + wn1.w * a1.w +
                  wn2.x * a2.x + wn2.y * a2.y + wn2.z * a2.z + wn2.w * a2.w +
                  wn3.x * a3.x + wn3.y * a3.y + wn3.z * a3.z + wn3.w * a3.w;
      float anB = wn0.x * b0.x + wn0.y * b0.y + wn0.z * b0.z + wn0.w * b0.w +
                  wn1.x * b1.x + wn1.y * b1.y + wn1.z * b1.z + wn1.w * b1.w +
                  wn2.x * b2.x + wn2.y * b2.y + wn2.z * b2.z + wn2.w * b2.w +
                  wn3.x * b3.x + wn3.y * b3.y + wn3.z * b3.z + wn3.w * b3.w;
      arA += __shfl_xor(arA, 32, 64);
      arB += __shfl_xor(arB, 32, 64);
      azA += __shfl_xor(azA, 32, 64);
      azB += __shfl_xor(azB, 32, 64);
      anA += __shfl_xor(anA, 32, 64);
      anB += __shfl_xor(anB, 32, 64);
      float rA = sigm(grA + arA + bhr);
      float rB = sigm(grB + arB + bhr);
      float zA = sigm(gzA + azA + bhz);
      float zB = sigm(gzB + azB + bhz);
      float nnA = tanh_fast(gnA + rA * (anA + bhn));
      float nnB = tanh_fast(gnB + rB * (anB + bhn));
      hA = (1.f - zA) * nnA + zA * hA;
      hB = (1.f - zB) * nnB + zB * hB;
      if (jh == 0) { h_buf[wv][k] = hA; h_buf[wv][36 + k] = hB; }
      float poA = p1k * hA;
      float poB = p1k * hB;
#pragma unroll
      for (int off = 16; off >= 1; off >>= 1) {
        poA += __shfl_xor(poA, off, 64);
        poB += __shfl_xor(poB, off, 64);
      }
      if (l == 0) {
        s_o[nlA][t] = poA + p1b0;
        if (hasB) s_o[nlB][t] = poB + p1b0;
      }
    }
    if (l < TSTEPS) {
      float accA = p2b[l], accB = accA;
#pragma unroll
      for (int s2 = 0; s2 < TSTEPS; ++s2) {
        float w = p2w[l * TSTEPS + s2];
        accA += w * s_o[nlA][s2];
        accB += w * s_o[nlBc][s2];
      }
      out[(size_t)nodeA * TSTEPS + l] = accA;
      if (hasB) out[(size_t)nodeB * TSTEPS + l] = accB;
    }
  }
}

// ---------------------------------------------------------------------------
extern "C" void kernel_launch(void* const* d_in, const int* in_sizes, int n_in,
                              void* d_out, int out_size, void* d_ws,
                              size_t ws_size, hipStream_t stream) {
  const float* x = (const float*)d_in[0];
  const int* ei = (const int*)d_in[1];
  const float* lin_w = (const float*)d_in[2];
  const float* att_src = (const float*)d_in[3];
  const float* att_dst = (const float*)d_in[4];
  const float* gat_bias = (const float*)d_in[5];
  const float* w_ih = (const float*)d_in[6];
  const float* w_hh = (const float*)d_in[7];
  const float* b_ih = (const float*)d_in[8];
  const float* b_hh = (const float*)d_in[9];
  const float* p1w = (const float*)d_in[10];
  const float* p1b = (const float*)d_in[11];
  const float* p2w = (const float*)d_in[12];
  const float* p2b = (const float*)d_in[13];

  int N = in_sizes[0] / GAT_IN;  // 10000
  int E = in_sizes[1] / 2;       // 160000
  int ET = E + N;

  size_t off = 0;
  char* base = (char*)d_ws;
  auto alloc = [&](size_t bytes) {
    void* p = base + off;
    off += (bytes + 255) & ~(size_t)255;
    return p;
  };
  unsigned short* Yb = (unsigned short*)alloc((size_t)N * 72 * 2);  // bf16 Y
  unsigned short* WWt = (unsigned short*)alloc((size_t)12 * 96 * 96 * 2);
  float* biasb = (float*)alloc((size_t)12 * 96 * 4);
  float* vbuf = (float*)alloc(144 * 4);
  int* cnt = (int*)alloc((size_t)N * 4);
  int* slist = (int*)alloc((size_t)N * SLOTS * 4);
  (void)ws_size; (void)n_in; (void)out_size;

  int zero_blocks = (N + 95) / 96;  // 105
  k_const<<<948 + zero_blocks, 96, 0, stream>>>(lin_w, gat_bias, w_ih, b_ih,
                                                att_src, att_dst, WWt, biasb,
                                                vbuf, cnt, N);
  k_place<<<(ET + 255) / 256, 256, 0, stream>>>(ei, ei + E, cnt, slist, E, ET);
  k_aggx<<<(N + 3) / 4, 256, 0, stream>>>(x, vbuf, slist, cnt, Yb, N);
  k_gmr<<<(N + 15) / 16, 512, 0, stream>>>(Yb, WWt, biasb, w_hh, b_hh, p1w,
                                           p1b, p2w, p2b, (float*)d_out, N);
}